// Round 2
// baseline (581.528 us; speedup 1.0000x reference)
//
#include <hip/hip_runtime.h>

// ---------------- constants ----------------
#define BB 4
#define TT 4096
#define DD 256
#define KQ 32
#define TOPK 4
#define NV 8
#define NL 4
#define MROWS (BB*TT)   // 16384
#define NCH 8           // s-chunks for topk
#define SCH 512         // s per chunk

typedef __attribute__((ext_vector_type(8))) __bf16 bf16x8;
typedef __attribute__((ext_vector_type(4))) float  f32x4;

__device__ __forceinline__ unsigned short f2bf(float f) {
  union { float f; unsigned u; } un; un.f = f;
  unsigned r = un.u + 0x7fffu + ((un.u >> 16) & 1u);
  return (unsigned short)(r >> 16);
}
__device__ __forceinline__ float b2f(unsigned short s) {
  union { unsigned u; float f; } un; un.u = ((unsigned)s) << 16;
  return un.f;
}

// ---------------- weight prep: transpose + bf16 convert ----------------
// W1f [256][512] -> W1ft [512][256]; W2f [512][256] -> W2ft [256][512]
// opW1 [8][256][256] -> opW1t [(v,e)=2048][256]; opW2 [8][256][256] -> opW2t [256][(v,k)=2048]
// Whh [768][256] -> Whht [256][768] (f32)
__global__ __launch_bounds__(256) void prep_weights(
    const float* __restrict__ W1f, const float* __restrict__ W2f,
    const float* __restrict__ opW1, const float* __restrict__ opW2,
    const float* __restrict__ Whh,
    unsigned short* __restrict__ W1ft, unsigned short* __restrict__ W2ft,
    unsigned short* __restrict__ opW1t, unsigned short* __restrict__ opW2t,
    float* __restrict__ Whht) {
  int idx = blockIdx.x * 256 + threadIdx.x;
  if (idx < 131072) { int n = idx >> 8, d = idx & 255; W1ft[idx] = f2bf(W1f[d*512 + n]); return; }
  idx -= 131072;
  if (idx < 131072) { int n = idx >> 9, d = idx & 511; W2ft[idx] = f2bf(W2f[d*256 + n]); return; }
  idx -= 131072;
  if (idx < 524288) { int np = idx >> 8, d = idx & 255; int v = np >> 8, e = np & 255;
                      opW1t[idx] = f2bf(opW1[v*65536 + d*256 + e]); return; }
  idx -= 524288;
  if (idx < 524288) { int n = idx >> 11, kp = idx & 2047; int v = kp >> 8, k2 = kp & 255;
                      opW2t[idx] = f2bf(opW2[v*65536 + k2*256 + n]); return; }
  idx -= 524288;
  if (idx < 196608) { int d = idx / 768, j = idx - d*768; Whht[idx] = Whh[j*256 + d]; return; }
}

// ---------------- q/k projection (fp32) ----------------
__global__ __launch_bounds__(256) void qk_proj(
    const float* __restrict__ x, const float* __restrict__ Wq, const float* __restrict__ bq,
    const float* __restrict__ Wk, const float* __restrict__ bk,
    float* __restrict__ q, float* __restrict__ kk) {
  __shared__ float xs[1024];
  int tid = threadIdx.x;
  *(float4*)&xs[tid*4] = *(const float4*)&x[(size_t)blockIdx.x*1024 + tid*4];
  __syncthreads();
  int row = blockIdx.x*4 + (tid >> 6);
  int j = tid & 63;
  int jj = j & 31;
  const float* W = (j < 32) ? Wq : Wk;
  const float* xr = &xs[(tid >> 6) * 256];
  float acc = 0.f;
  #pragma unroll 8
  for (int d = 0; d < 256; ++d) acc += xr[d] * W[d*32 + jj];
  acc += (j < 32) ? bq[jj] : bk[jj];
  float* out = (j < 32) ? q : kk;
  out[(size_t)row*32 + jj] = acc;
}

// ---------------- sim + per-chunk top4 ----------------
__device__ __forceinline__ void ins4(float val, int s, float v[4], int id[4]) {
  if (val > v[3]) {
    if (val > v[1]) {
      v[3] = v[2]; id[3] = id[2];
      if (val > v[0]) { v[2]=v[1]; id[2]=id[1]; v[1]=v[0]; id[1]=id[0]; v[0]=val; id[0]=s; }
      else            { v[2]=v[1]; id[2]=id[1]; v[1]=val; id[1]=s; }
    } else {
      if (val > v[2]) { v[3]=v[2]; id[3]=id[2]; v[2]=val; id[2]=s; }
      else            { v[3]=val; id[3]=s; }
    }
  }
}

__global__ __launch_bounds__(256) void sim_topk(
    const float* __restrict__ q, const float* __restrict__ k,
    const float* __restrict__ mask,
    float* __restrict__ candv, int* __restrict__ candi) {
  int b = blockIdx.z, rg = blockIdx.y, ch = blockIdx.x;
  int tid = threadIdx.x;
  int t0 = rg * 512;
  int ta = t0 + tid, tb = t0 + 256 + tid;
  float4 qa[8], qb[8];
  const float4* qpa = (const float4*)&q[((size_t)b*TT + ta)*32];
  const float4* qpb = (const float4*)&q[((size_t)b*TT + tb)*32];
  #pragma unroll
  for (int i = 0; i < 8; ++i) { qa[i] = qpa[i]; qb[i] = qpb[i]; }
  float mta = mask[b*TT + ta], mtb = mask[b*TT + tb];
  float va[4], vb[4]; int ia[4], ib[4];
  #pragma unroll
  for (int r = 0; r < 4; ++r) { va[r] = -__builtin_inff(); vb[r] = -__builtin_inff(); ia[r] = 0x7fffffff; ib[r] = 0x7fffffff; }
  __shared__ float ks[256*32];
  __shared__ float ms[256];
  int s0 = ch * SCH;
  for (int sb = 0; sb < 2; ++sb) {
    __syncthreads();
    const float* ksrc = &k[((size_t)b*TT + s0 + sb*256)*32];
    #pragma unroll
    for (int i = 0; i < 8; ++i)
      *(float4*)&ks[i*1024 + tid*4] = *(const float4*)&ksrc[i*1024 + tid*4];
    ms[tid] = mask[b*TT + s0 + sb*256 + tid];
    __syncthreads();
    for (int ss = 0; ss < 256; ++ss) {
      const float4* kr = (const float4*)&ks[ss*32];
      float d0a=0.f, d1a=0.f, d0b=0.f, d1b=0.f;
      #pragma unroll
      for (int i = 0; i < 8; i += 2) {
        float4 k0 = kr[i], k1 = kr[i+1];
        d0a += qa[i].x*k0.x + qa[i].y*k0.y + qa[i].z*k0.z + qa[i].w*k0.w;
        d1a += qa[i+1].x*k1.x + qa[i+1].y*k1.y + qa[i+1].z*k1.z + qa[i+1].w*k1.w;
        d0b += qb[i].x*k0.x + qb[i].y*k0.y + qb[i].z*k0.z + qb[i].w*k0.w;
        d1b += qb[i+1].x*k1.x + qb[i+1].y*k1.y + qb[i+1].z*k1.z + qb[i+1].w*k1.w;
      }
      float sm = ms[ss];
      int s = s0 + sb*256 + ss;
      float sa  = (mta*sm == 0.0f) ? -1e9f : (d0a + d1a);
      float sbv = (mtb*sm == 0.0f) ? -1e9f : (d0b + d1b);
      ins4(sa, s, va, ia);
      ins4(sbv, s, vb, ib);
    }
  }
  size_t base_a = ((size_t)(b*TT + ta)*NCH + ch)*4;
  size_t base_b = ((size_t)(b*TT + tb)*NCH + ch)*4;
  #pragma unroll
  for (int r = 0; r < 4; ++r) {
    candv[base_a+r] = va[r]; candi[base_a+r] = ia[r];
    candv[base_b+r] = vb[r]; candi[base_b+r] = ib[r];
  }
}

// ---------------- merge top4 + gather + routed_mean (bf16 out) ----------------
__global__ __launch_bounds__(256) void merge_gather(
    const float* __restrict__ candv, const int* __restrict__ candi,
    const float* __restrict__ x, unsigned short* __restrict__ rmb) {
  int block0 = blockIdx.x * 64;
  __shared__ int sidx[64*4];
  int tid = threadIdx.x;
  if (tid < 64) {
    int row = block0 + tid;
    const float* cv = &candv[(size_t)row*32];
    const int*   ci = &candi[(size_t)row*32];
    int c0 = -1, c1 = -1, c2 = -1, c3 = -1;
    #pragma unroll
    for (int r = 0; r < 4; ++r) {
      float bv = -__builtin_inff(); int bi = 0x7fffffff;
      for (int j = 0; j < 32; ++j) {
        float v = cv[j]; int ii = ci[j];
        if (ii == c0 || ii == c1 || ii == c2 || ii == c3) continue;
        if (v > bv || (v == bv && ii < bi)) { bv = v; bi = ii; }
      }
      if (r == 0) c0 = bi; else if (r == 1) c1 = bi; else if (r == 2) c2 = bi; else c3 = bi;
      sidx[tid*4 + r] = bi;
    }
  }
  __syncthreads();
  int rl = tid >> 2;
  int dq = (tid & 3) * 64;
  int row = block0 + rl;
  int b = row >> 12;
  int i0 = sidx[rl*4+0], i1 = sidx[rl*4+1], i2 = sidx[rl*4+2], i3 = sidx[rl*4+3];
  const float* xb = &x[(size_t)b*TT*DD];
  #pragma unroll
  for (int d = 0; d < 64; d += 4) {
    float4 a = *(const float4*)&xb[(size_t)i0*DD + dq + d];
    float4 bb = *(const float4*)&xb[(size_t)i1*DD + dq + d];
    float4 c = *(const float4*)&xb[(size_t)i2*DD + dq + d];
    float4 e = *(const float4*)&xb[(size_t)i3*DD + dq + d];
    unsigned short o0 = f2bf((a.x+bb.x+c.x+e.x)*0.25f);
    unsigned short o1 = f2bf((a.y+bb.y+c.y+e.y)*0.25f);
    unsigned short o2 = f2bf((a.z+bb.z+c.z+e.z)*0.25f);
    unsigned short o3 = f2bf((a.w+bb.w+c.w+e.w)*0.25f);
    unsigned short* dst = &rmb[(size_t)row*DD + dq + d];
    dst[0] = o0; dst[1] = o1; dst[2] = o2; dst[3] = o3;
  }
}

// ---------------- bf16 MFMA GEMM: C[M,N] = A[M,K] @ Bt[N,K]^T, epilogue variants ----------------
// EPI 0: outB = bf16(gelu(acc + bias[n]))                        (FFN1)
// EPI 1: outF = acc + bias[n] + b2f(resB[row,n])                 (FFN2 + residual)
// EPI 2: outB = bf16(relu(acc + bias[n]) * auxf[b*8 + n/256])    (op GEMM-A, w folded)
// EPI 3: outB = bf16(acc + auxf[b*256 + n])                      (op GEMM-B + wb2)
template<int EPI>
__global__ __launch_bounds__(256) void gemm_bf16(
    const unsigned short* __restrict__ A, const unsigned short* __restrict__ Bt,
    int Ndim, int Kdim,
    const float* __restrict__ bias,
    const unsigned short* __restrict__ resB,
    const float* __restrict__ auxf,
    float* __restrict__ outF, unsigned short* __restrict__ outB) {
  __shared__ unsigned short As[128*64];
  __shared__ unsigned short Bs[128*64];
  int tid = threadIdx.x;
  int lane = tid & 63, wid = tid >> 6;
  int wm = wid >> 1, wn = wid & 1;
  int l16 = lane & 15, lhi = lane >> 4;
  int m0 = blockIdx.x * 128, n0 = blockIdx.y * 128;
  f32x4 acc[4][4] = {};
  for (int kt = 0; kt < Kdim; kt += 64) {
    __syncthreads();
    #pragma unroll
    for (int i = 0; i < 4; ++i) {
      int L = i*256 + tid;
      int r = L >> 3, c = L & 7;
      int cs = c ^ (r & 7);
      uint4 va = *(const uint4*)(A  + (size_t)(m0 + r)*Kdim + kt + c*8);
      *(uint4*)&As[r*64 + cs*8] = va;
      uint4 vb = *(const uint4*)(Bt + (size_t)(n0 + r)*Kdim + kt + c*8);
      *(uint4*)&Bs[r*64 + cs*8] = vb;
    }
    __syncthreads();
    #pragma unroll
    for (int ks = 0; ks < 2; ++ks) {
      bf16x8 af[4], bfr[4];
      int kc = ks*4 + lhi;
      #pragma unroll
      for (int f = 0; f < 4; ++f) {
        int ra = wm*64 + f*16 + l16;
        af[f]  = *(const bf16x8*)&As[ra*64 + ((kc ^ (ra & 7)))*8];
        int rb = wn*64 + f*16 + l16;
        bfr[f] = *(const bf16x8*)&Bs[rb*64 + ((kc ^ (rb & 7)))*8];
      }
      #pragma unroll
      for (int mf = 0; mf < 4; ++mf)
        #pragma unroll
        for (int nf = 0; nf < 4; ++nf)
          acc[mf][nf] = __builtin_amdgcn_mfma_f32_16x16x32_bf16(af[mf], bfr[nf], acc[mf][nf], 0, 0, 0);
    }
  }
  #pragma unroll
  for (int mf = 0; mf < 4; ++mf) {
    #pragma unroll
    for (int nf = 0; nf < 4; ++nf) {
      #pragma unroll
      for (int r = 0; r < 4; ++r) {
        int row = m0 + wm*64 + mf*16 + lhi*4 + r;
        int col = n0 + wn*64 + nf*16 + l16;
        float v = acc[mf][nf][r];
        if constexpr (EPI == 0) {
          v += bias[col];
          v = 0.5f * v * (1.0f + erff(v * 0.70710678118654752f));
          outB[(size_t)row*Ndim + col] = f2bf(v);
        } else if constexpr (EPI == 1) {
          v += bias[col] + b2f(resB[(size_t)row*Ndim + col]);
          outF[(size_t)row*Ndim + col] = v;
        } else if constexpr (EPI == 2) {
          v += bias[col];
          v = fmaxf(v, 0.0f) * auxf[(row >> 12)*8 + (col >> 8)];
          outB[(size_t)row*Ndim + col] = f2bf(v);
        } else {
          v += auxf[(row >> 12)*256 + col];
          outB[(size_t)row*Ndim + col] = f2bf(v);
        }
      }
    }
  }
}

// ---------------- LayerNorm (row=256) -> h bf16 ----------------
__global__ __launch_bounds__(256) void ln_kernel(
    const float* __restrict__ preLN, const float* __restrict__ g,
    const float* __restrict__ bta, unsigned short* __restrict__ h) {
  __shared__ float red[4];
  int row = blockIdx.x, tid = threadIdx.x;
  float v = preLN[(size_t)row*256 + tid];
  float s = v;
  #pragma unroll
  for (int o = 32; o > 0; o >>= 1) s += __shfl_down(s, o);
  if ((tid & 63) == 0) red[tid >> 6] = s;
  __syncthreads();
  float mu = (red[0] + red[1] + red[2] + red[3]) * (1.0f/256.0f);
  __syncthreads();
  float d = v - mu;
  float s2 = d * d;
  #pragma unroll
  for (int o = 32; o > 0; o >>= 1) s2 += __shfl_down(s2, o);
  if ((tid & 63) == 0) red[tid >> 6] = s2;
  __syncthreads();
  float var = (red[0] + red[1] + red[2] + red[3]) * (1.0f/256.0f);
  float out = d * rsqrtf(var + 1e-5f) * g[tid] + bta[tid];
  h[(size_t)row*256 + tid] = f2bf(out);
}

// ---------------- partial column-sum of h for hs ----------------
__global__ void hsum_kernel(const unsigned short* __restrict__ h, float* __restrict__ hpart) {
  int c = blockIdx.x, b = blockIdx.y, d = threadIdx.x;
  const unsigned short* hp = &h[((size_t)(b*TT + c*256))*256 + d];
  float s = 0.f;
  for (int i = 0; i < 256; ++i) s += b2f(hp[(size_t)i*256]);
  hpart[(b*16 + c)*256 + d] = s;
}

// ---------------- GRU + program logits + softmax-mean w + wb2 ----------------
__global__ __launch_bounds__(256) void gru_kernel(
    const float* __restrict__ hpart, const float* __restrict__ Whht,
    const float* __restrict__ b_ih, const float* __restrict__ b_hh,
    const float* __restrict__ Wp, const float* __restrict__ bp,
    const float* __restrict__ opb2, float* __restrict__ w, float* __restrict__ wb2) {
  int b = blockIdx.x, tid = threadIdx.x;
  __shared__ float hs[256];
  __shared__ float lg[8];
  __shared__ float wacc[8];
  float s = 0.f;
  for (int c = 0; c < 16; ++c) s += hpart[(b*16 + c)*256 + tid];
  hs[tid] = s * (1.0f/4096.0f);
  if (tid < 8) wacc[tid] = 0.f;
  __syncthreads();
  for (int l = 0; l < NL; ++l) {
    float g0 = 0.f, g1 = 0.f, g2 = 0.f;
    for (int d2 = 0; d2 < 256; ++d2) {
      float hv = hs[d2];
      g0 += Whht[d2*768 + tid]       * hv;
      g1 += Whht[d2*768 + 256 + tid] * hv;
      g2 += Whht[d2*768 + 512 + tid] * hv;
    }
    g0 += b_hh[tid]; g1 += b_hh[256 + tid]; g2 += b_hh[512 + tid];
    float r = 1.f / (1.f + expf(-(b_ih[tid] + g0)));
    float z = 1.f / (1.f + expf(-(b_ih[256 + tid] + g1)));
    float n = tanhf(b_ih[512 + tid] + r * g2);
    float hnew = (1.f - z) * n + z * hs[tid];
    __syncthreads();
    hs[tid] = hnew;
    __syncthreads();
    if (tid < 8) {
      float acc = bp[tid];
      for (int d2 = 0; d2 < 256; ++d2) acc += hs[d2] * Wp[d2*8 + tid];
      lg[tid] = acc;
    }
    __syncthreads();
    if (tid == 0) {
      float mx = lg[0];
      #pragma unroll
      for (int i = 1; i < 8; ++i) mx = fmaxf(mx, lg[i]);
      float sm = 0.f; float e[8];
      #pragma unroll
      for (int i = 0; i < 8; ++i) { e[i] = expf(lg[i] - mx); sm += e[i]; }
      #pragma unroll
      for (int i = 0; i < 8; ++i) wacc[i] += e[i] / sm;
    }
    __syncthreads();
  }
  if (tid < 8) w[b*8 + tid] = wacc[tid] * 0.25f;
  float acc = 0.f;
  #pragma unroll
  for (int v = 0; v < 8; ++v) acc += (wacc[v] * 0.25f) * opb2[v*256 + tid];
  wb2[b*256 + tid] = acc;
}

// ---------------- max-pool partials over t ----------------
__global__ void maxpool_kernel(const unsigned short* __restrict__ fusedB, float* __restrict__ mpart) {
  int c = blockIdx.x, b = blockIdx.y, d = threadIdx.x;
  const unsigned short* fp = &fusedB[((size_t)(b*TT + c*256))*256 + d];
  float m = -__builtin_inff();
  for (int i = 0; i < 256; ++i) m = fmaxf(m, b2f(fp[(size_t)i*256]));
  mpart[(b*16 + c)*256 + d] = m;
}

// ---------------- final: pooled @ Wo + bo ----------------
__global__ __launch_bounds__(256) void outproj_kernel(
    const float* __restrict__ mpart, const float* __restrict__ Wo,
    const float* __restrict__ bo, float* __restrict__ out) {
  int b = blockIdx.x, tid = threadIdx.x;
  __shared__ float pooled[256];
  float m = -__builtin_inff();
  for (int c = 0; c < 16; ++c) m = fmaxf(m, mpart[(b*16 + c)*256 + tid]);
  pooled[tid] = m;
  __syncthreads();
  float acc = bo[tid];
  for (int d = 0; d < 256; ++d) acc += pooled[d] * Wo[d*256 + tid];
  out[b*256 + tid] = acc;
}

// ---------------- host ----------------
extern "C" void kernel_launch(void* const* d_in, const int* in_sizes, int n_in,
                              void* d_out, int out_size, void* d_ws, size_t ws_size,
                              hipStream_t stream) {
  const float* x     = (const float*)d_in[0];
  const float* amask = (const float*)d_in[1];
  const float* Wq    = (const float*)d_in[2];
  const float* bq    = (const float*)d_in[3];
  const float* Wk    = (const float*)d_in[4];
  const float* bk    = (const float*)d_in[5];
  const float* W1f   = (const float*)d_in[8];
  const float* b1f   = (const float*)d_in[9];
  const float* W2f   = (const float*)d_in[10];
  const float* b2f   = (const float*)d_in[11];
  const float* ln_g  = (const float*)d_in[12];
  const float* ln_b  = (const float*)d_in[13];
  const float* Whh   = (const float*)d_in[14];
  const float* b_ih  = (const float*)d_in[15];
  const float* b_hh  = (const float*)d_in[16];
  const float* Wp    = (const float*)d_in[17];
  const float* bp    = (const float*)d_in[18];
  const float* opW1  = (const float*)d_in[19];
  const float* opb1  = (const float*)d_in[20];
  const float* opW2  = (const float*)d_in[21];
  const float* opb2  = (const float*)d_in[22];
  const float* Wo    = (const float*)d_in[23];
  const float* bo    = (const float*)d_in[24];
  (void)in_sizes; (void)n_in; (void)out_size; (void)ws_size;

  char* ws = (char*)d_ws;
  float*          q      = (float*)(ws + 0);
  float*          kk     = (float*)(ws + 2097152);
  float*          candv  = (float*)(ws + 4194304);
  int*            candi  = (int*)  (ws + 6291456);
  unsigned short* rmb    = (unsigned short*)(ws + 8388608);
  unsigned short* h      = (unsigned short*)(ws + 16777216);
  unsigned short* fusedB = (unsigned short*)(ws + 25165824);
  unsigned short* W1ft   = (unsigned short*)(ws + 33554432);
  unsigned short* W2ft   = (unsigned short*)(ws + 33816576);
  unsigned short* opW1t  = (unsigned short*)(ws + 34078720);
  unsigned short* opW2t  = (unsigned short*)(ws + 35127296);
  float*          Whht   = (float*)(ws + 36175872);
  float*          hpart  = (float*)(ws + 36962304);
  float*          wv     = (float*)(ws + 37027840);
  float*          wb2    = (float*)(ws + 37028096);
  float*          mpart  = (float*)(ws + 37032192);
  char*           arena  = ws + 37097728;
  unsigned short* G1     = (unsigned short*)arena;              // [16384,512] bf16 (FFN hidden)
  float*          preLN  = (float*)(arena + 16777216);          // [16384,256] f32
  unsigned short* G1all  = (unsigned short*)arena;              // [16384,2048] bf16 (op hidden, w-scaled)

  prep_weights<<<5888, 256, 0, stream>>>(W1f, W2f, opW1, opW2, Whh, W1ft, W2ft, opW1t, opW2t, Whht);
  qk_proj<<<4096, 256, 0, stream>>>(x, Wq, bq, Wk, bk, q, kk);
  sim_topk<<<dim3(NCH, 8, BB), 256, 0, stream>>>(q, kk, amask, candv, candi);
  merge_gather<<<256, 256, 0, stream>>>(candv, candi, x, rmb);
  gemm_bf16<0><<<dim3(128, 4), 256, 0, stream>>>(rmb, W1ft, 512, 256, b1f, nullptr, nullptr, nullptr, G1);
  gemm_bf16<1><<<dim3(128, 2), 256, 0, stream>>>(G1, W2ft, 256, 512, b2f, rmb, nullptr, preLN, nullptr);
  ln_kernel<<<16384, 256, 0, stream>>>(preLN, ln_g, ln_b, h);
  hsum_kernel<<<dim3(16, 4), 256, 0, stream>>>(h, hpart);
  gru_kernel<<<4, 256, 0, stream>>>(hpart, Whht, b_ih, b_hh, Wp, bp, opb2, wv, wb2);
  gemm_bf16<2><<<dim3(128, 16), 256, 0, stream>>>(h, opW1t, 2048, 256, opb1, nullptr, wv, nullptr, G1all);
  gemm_bf16<3><<<dim3(128, 2), 256, 0, stream>>>(G1all, opW2t, 256, 2048, nullptr, nullptr, wb2, nullptr, fusedB);
  maxpool_kernel<<<dim3(16, 4), 256, 0, stream>>>(fusedB, mpart);
  outproj_kernel<<<4, 256, 0, stream>>>(mpart, Wo, bo, (float*)d_out);
}

// Round 3
// 507.157 us; speedup vs baseline: 1.1466x; 1.1466x over previous
//
#include <hip/hip_runtime.h>

// ---------------- constants ----------------
#define BB 4
#define TT 4096
#define DD 256
#define KQ 32
#define TOPK 4
#define NV 8
#define NL 4
#define MROWS (BB*TT)   // 16384
#define NCH 32          // s-chunks for topk
#define SCH 128         // s per chunk
#define NC  (NCH*TOPK)  // 128 candidates per row

typedef __attribute__((ext_vector_type(8))) __bf16 bf16x8;
typedef __attribute__((ext_vector_type(4))) float  f32x4;

__device__ __forceinline__ unsigned short f2bf(float f) {
  union { float f; unsigned u; } un; un.f = f;
  unsigned r = un.u + 0x7fffu + ((un.u >> 16) & 1u);
  return (unsigned short)(r >> 16);
}
__device__ __forceinline__ float b2f(unsigned short s) {
  union { unsigned u; float f; } un; un.u = ((unsigned)s) << 16;
  return un.f;
}

// ---------------- weight prep: transpose + bf16 convert ----------------
__global__ __launch_bounds__(256) void prep_weights(
    const float* __restrict__ W1f, const float* __restrict__ W2f,
    const float* __restrict__ opW1, const float* __restrict__ opW2,
    const float* __restrict__ Whh,
    unsigned short* __restrict__ W1ft, unsigned short* __restrict__ W2ft,
    unsigned short* __restrict__ opW1t, unsigned short* __restrict__ opW2t,
    float* __restrict__ Whht) {
  int idx = blockIdx.x * 256 + threadIdx.x;
  if (idx < 131072) { int n = idx >> 8, d = idx & 255; W1ft[idx] = f2bf(W1f[d*512 + n]); return; }
  idx -= 131072;
  if (idx < 131072) { int n = idx >> 9, d = idx & 511; W2ft[idx] = f2bf(W2f[d*256 + n]); return; }
  idx -= 131072;
  if (idx < 524288) { int np = idx >> 8, d = idx & 255; int v = np >> 8, e = np & 255;
                      opW1t[idx] = f2bf(opW1[v*65536 + d*256 + e]); return; }
  idx -= 524288;
  if (idx < 524288) { int n = idx >> 11, kp = idx & 2047; int v = kp >> 8, k2 = kp & 255;
                      opW2t[idx] = f2bf(opW2[v*65536 + k2*256 + n]); return; }
  idx -= 524288;
  if (idx < 196608) { int d = idx / 768, j = idx - d*768; Whht[idx] = Whh[j*256 + d]; return; }
}

// ---------------- q/k projection (fp32) ----------------
__global__ __launch_bounds__(256) void qk_proj(
    const float* __restrict__ x, const float* __restrict__ Wq, const float* __restrict__ bq,
    const float* __restrict__ Wk, const float* __restrict__ bk,
    float* __restrict__ q, float* __restrict__ kk) {
  __shared__ float xs[1024];
  int tid = threadIdx.x;
  *(float4*)&xs[tid*4] = *(const float4*)&x[(size_t)blockIdx.x*1024 + tid*4];
  __syncthreads();
  int row = blockIdx.x*4 + (tid >> 6);
  int j = tid & 63;
  int jj = j & 31;
  const float* W = (j < 32) ? Wq : Wk;
  const float* xr = &xs[(tid >> 6) * 256];
  float acc = 0.f;
  #pragma unroll 8
  for (int d = 0; d < 256; ++d) acc += xr[d] * W[d*32 + jj];
  acc += (j < 32) ? bq[jj] : bk[jj];
  float* out = (j < 32) ? q : kk;
  out[(size_t)row*32 + jj] = acc;
}

// ---------------- sim + per-chunk top4 ----------------
__device__ __forceinline__ void ins4(float val, int s, float v[4], int id[4]) {
  if (val > v[3]) {
    if (val > v[1]) {
      v[3] = v[2]; id[3] = id[2];
      if (val > v[0]) { v[2]=v[1]; id[2]=id[1]; v[1]=v[0]; id[1]=id[0]; v[0]=val; id[0]=s; }
      else            { v[2]=v[1]; id[2]=id[1]; v[1]=val; id[1]=s; }
    } else {
      if (val > v[2]) { v[3]=v[2]; id[3]=id[2]; v[2]=val; id[2]=s; }
      else            { v[3]=val; id[3]=s; }
    }
  }
}

__global__ __launch_bounds__(256) void sim_topk(
    const float* __restrict__ q, const float* __restrict__ k,
    const float* __restrict__ mask,
    float* __restrict__ candv, int* __restrict__ candi) {
  int b = blockIdx.z, rg = blockIdx.y, ch = blockIdx.x;
  int tid = threadIdx.x;
  int t0 = rg * 512;
  int ta = t0 + tid, tb = t0 + 256 + tid;
  float4 qa[8], qb[8];
  const float4* qpa = (const float4*)&q[((size_t)b*TT + ta)*32];
  const float4* qpb = (const float4*)&q[((size_t)b*TT + tb)*32];
  #pragma unroll
  for (int i = 0; i < 8; ++i) { qa[i] = qpa[i]; qb[i] = qpb[i]; }
  float mta = mask[b*TT + ta], mtb = mask[b*TT + tb];
  float va[4], vb[4]; int ia[4], ib[4];
  #pragma unroll
  for (int r = 0; r < 4; ++r) { va[r] = -__builtin_inff(); vb[r] = -__builtin_inff(); ia[r] = 0x7fffffff; ib[r] = 0x7fffffff; }
  __shared__ float ks[SCH*32];
  __shared__ float ms[SCH];
  int s0 = ch * SCH;
  const float* ksrc = &k[((size_t)b*TT + s0)*32];
  #pragma unroll
  for (int i = 0; i < 4; ++i)
    *(float4*)&ks[i*1024 + tid*4] = *(const float4*)&ksrc[i*1024 + tid*4];
  if (tid < SCH) ms[tid] = mask[b*TT + s0 + tid];
  __syncthreads();
  for (int ss = 0; ss < SCH; ++ss) {
    const float4* kr = (const float4*)&ks[ss*32];
    float d0a=0.f, d1a=0.f, d0b=0.f, d1b=0.f;
    #pragma unroll
    for (int i = 0; i < 8; i += 2) {
      float4 k0 = kr[i], k1 = kr[i+1];
      d0a += qa[i].x*k0.x + qa[i].y*k0.y + qa[i].z*k0.z + qa[i].w*k0.w;
      d1a += qa[i+1].x*k1.x + qa[i+1].y*k1.y + qa[i+1].z*k1.z + qa[i+1].w*k1.w;
      d0b += qb[i].x*k0.x + qb[i].y*k0.y + qb[i].z*k0.z + qb[i].w*k0.w;
      d1b += qb[i+1].x*k1.x + qb[i+1].y*k1.y + qb[i+1].z*k1.z + qb[i+1].w*k1.w;
    }
    float sm = ms[ss];
    int s = s0 + ss;
    float sa  = (mta*sm == 0.0f) ? -1e9f : (d0a + d1a);
    float sbv = (mtb*sm == 0.0f) ? -1e9f : (d0b + d1b);
    ins4(sa, s, va, ia);
    ins4(sbv, s, vb, ib);
  }
  size_t base_a = ((size_t)(b*TT + ta)*NCH + ch)*4;
  size_t base_b = ((size_t)(b*TT + tb)*NCH + ch)*4;
  #pragma unroll
  for (int r = 0; r < 4; ++r) {
    candv[base_a+r] = va[r]; candi[base_a+r] = ia[r];
    candv[base_b+r] = vb[r]; candi[base_b+r] = ib[r];
  }
}

// ---------------- merge top4 (128 cands) + gather + routed_mean ----------------
__global__ __launch_bounds__(256) void merge_gather(
    const float* __restrict__ candv, const int* __restrict__ candi,
    const float* __restrict__ x, unsigned short* __restrict__ rmb) {
  int block0 = blockIdx.x * 64;
  int tid = threadIdx.x;
  __shared__ float svals[64*129];
  __shared__ int   sint [64*129];
  __shared__ int   sout [64*4];
  // stage 64 rows x 128 candidates (coalesced)
  #pragma unroll
  for (int it = 0; it < 32; ++it) {
    int flat = it*256 + tid;
    int r = flat >> 7, j = flat & 127;
    size_t g = (size_t)block0*NC + flat;
    svals[r*129 + j] = candv[g];
    sint [r*129 + j] = candi[g];
  }
  __syncthreads();
  if (tid < 64) {
    const float* cv = &svals[tid*129];
    const int*   ci = &sint [tid*129];
    int c0 = -1, c1 = -1, c2 = -1, c3 = -1;
    #pragma unroll
    for (int r = 0; r < 4; ++r) {
      float bv = -__builtin_inff(); int bi = 0x7fffffff;
      for (int j = 0; j < NC; ++j) {
        float v = cv[j]; int ii = ci[j];
        if (ii == c0 || ii == c1 || ii == c2 || ii == c3) continue;
        if (v > bv || (v == bv && ii < bi)) { bv = v; bi = ii; }
      }
      if (r == 0) c0 = bi; else if (r == 1) c1 = bi; else if (r == 2) c2 = bi; else c3 = bi;
      sout[tid*4 + r] = bi;
    }
  }
  __syncthreads();
  int rl = tid >> 2;
  int dq = (tid & 3) * 64;
  int row = block0 + rl;
  int b = row >> 12;
  int i0 = sout[rl*4+0], i1 = sout[rl*4+1], i2 = sout[rl*4+2], i3 = sout[rl*4+3];
  const float* xb = &x[(size_t)b*TT*DD];
  #pragma unroll
  for (int d = 0; d < 64; d += 4) {
    float4 a = *(const float4*)&xb[(size_t)i0*DD + dq + d];
    float4 bb = *(const float4*)&xb[(size_t)i1*DD + dq + d];
    float4 c = *(const float4*)&xb[(size_t)i2*DD + dq + d];
    float4 e = *(const float4*)&xb[(size_t)i3*DD + dq + d];
    unsigned short o0 = f2bf((a.x+bb.x+c.x+e.x)*0.25f);
    unsigned short o1 = f2bf((a.y+bb.y+c.y+e.y)*0.25f);
    unsigned short o2 = f2bf((a.z+bb.z+c.z+e.z)*0.25f);
    unsigned short o3 = f2bf((a.w+bb.w+c.w+e.w)*0.25f);
    unsigned short* dst = &rmb[(size_t)row*DD + dq + d];
    dst[0] = o0; dst[1] = o1; dst[2] = o2; dst[3] = o3;
  }
}

// ---------------- bf16 MFMA GEMM (128x128 tile), epilogue variants ----------------
template<int EPI>
__global__ __launch_bounds__(256) void gemm_bf16(
    const unsigned short* __restrict__ A, const unsigned short* __restrict__ Bt,
    int Ndim, int Kdim,
    const float* __restrict__ bias,
    const unsigned short* __restrict__ resB,
    const float* __restrict__ auxf,
    float* __restrict__ outF, unsigned short* __restrict__ outB) {
  __shared__ unsigned short As[128*64];
  __shared__ unsigned short Bs[128*64];
  int tid = threadIdx.x;
  int lane = tid & 63, wid = tid >> 6;
  int wm = wid >> 1, wn = wid & 1;
  int l16 = lane & 15, lhi = lane >> 4;
  int m0 = blockIdx.x * 128, n0 = blockIdx.y * 128;
  f32x4 acc[4][4] = {};
  for (int kt = 0; kt < Kdim; kt += 64) {
    __syncthreads();
    #pragma unroll
    for (int i = 0; i < 4; ++i) {
      int L = i*256 + tid;
      int r = L >> 3, c = L & 7;
      int cs = c ^ (r & 7);
      uint4 va = *(const uint4*)(A  + (size_t)(m0 + r)*Kdim + kt + c*8);
      *(uint4*)&As[r*64 + cs*8] = va;
      uint4 vb = *(const uint4*)(Bt + (size_t)(n0 + r)*Kdim + kt + c*8);
      *(uint4*)&Bs[r*64 + cs*8] = vb;
    }
    __syncthreads();
    #pragma unroll
    for (int ks = 0; ks < 2; ++ks) {
      bf16x8 af[4], bfr[4];
      int kc = ks*4 + lhi;
      #pragma unroll
      for (int f = 0; f < 4; ++f) {
        int ra = wm*64 + f*16 + l16;
        af[f]  = *(const bf16x8*)&As[ra*64 + ((kc ^ (ra & 7)))*8];
        int rb = wn*64 + f*16 + l16;
        bfr[f] = *(const bf16x8*)&Bs[rb*64 + ((kc ^ (rb & 7)))*8];
      }
      #pragma unroll
      for (int mf = 0; mf < 4; ++mf)
        #pragma unroll
        for (int nf = 0; nf < 4; ++nf)
          acc[mf][nf] = __builtin_amdgcn_mfma_f32_16x16x32_bf16(af[mf], bfr[nf], acc[mf][nf], 0, 0, 0);
    }
  }
  #pragma unroll
  for (int mf = 0; mf < 4; ++mf) {
    #pragma unroll
    for (int nf = 0; nf < 4; ++nf) {
      #pragma unroll
      for (int r = 0; r < 4; ++r) {
        int row = m0 + wm*64 + mf*16 + lhi*4 + r;
        int col = n0 + wn*64 + nf*16 + l16;
        float v = acc[mf][nf][r];
        if constexpr (EPI == 0) {
          v += bias[col];
          v = 0.5f * v * (1.0f + erff(v * 0.70710678118654752f));
          outB[(size_t)row*Ndim + col] = f2bf(v);
        } else if constexpr (EPI == 1) {
          v += bias[col] + b2f(resB[(size_t)row*Ndim + col]);
          outF[(size_t)row*Ndim + col] = v;
        } else if constexpr (EPI == 2) {
          v += bias[col];
          v = fmaxf(v, 0.0f) * auxf[(row >> 12)*8 + (col >> 8)];
          outB[(size_t)row*Ndim + col] = f2bf(v);
        } else {
          v += auxf[(row >> 12)*256 + col];
          outB[(size_t)row*Ndim + col] = f2bf(v);
        }
      }
    }
  }
}

// ---------------- LayerNorm: one wave per row ----------------
__global__ __launch_bounds__(256) void ln_kernel(
    const float* __restrict__ preLN, const float* __restrict__ g,
    const float* __restrict__ bta, unsigned short* __restrict__ h) {
  int tid = threadIdx.x;
  int lane = tid & 63;
  int row = blockIdx.x*4 + (tid >> 6);
  float4 v = *(const float4*)&preLN[(size_t)row*256 + lane*4];
  float s = v.x + v.y + v.z + v.w;
  #pragma unroll
  for (int o = 32; o > 0; o >>= 1) s += __shfl_xor(s, o);
  float mu = s * (1.0f/256.0f);
  float4 d; d.x = v.x-mu; d.y = v.y-mu; d.z = v.z-mu; d.w = v.w-mu;
  float s2 = d.x*d.x + d.y*d.y + d.z*d.z + d.w*d.w;
  #pragma unroll
  for (int o = 32; o > 0; o >>= 1) s2 += __shfl_xor(s2, o);
  float rstd = rsqrtf(s2 * (1.0f/256.0f) + 1e-5f);
  float4 gv = *(const float4*)&g[lane*4];
  float4 bv = *(const float4*)&bta[lane*4];
  ushort4 o;
  o.x = f2bf(d.x*rstd*gv.x + bv.x);
  o.y = f2bf(d.y*rstd*gv.y + bv.y);
  o.z = f2bf(d.z*rstd*gv.z + bv.z);
  o.w = f2bf(d.w*rstd*gv.w + bv.w);
  *(ushort4*)&h[(size_t)row*256 + lane*4] = o;
}

// ---------------- partial column-sum of h for hs ----------------
__global__ void hsum_kernel(const unsigned short* __restrict__ h, float* __restrict__ hpart) {
  int c = blockIdx.x, b = blockIdx.y, d = threadIdx.x;
  const unsigned short* hp = &h[((size_t)(b*TT + c*256))*256 + d];
  float s = 0.f;
  for (int i = 0; i < 256; ++i) s += b2f(hp[(size_t)i*256]);
  hpart[(b*16 + c)*256 + d] = s;
}

// ---------------- GRU + program logits + softmax-mean w + wb2 ----------------
__global__ __launch_bounds__(256) void gru_kernel(
    const float* __restrict__ hpart, const float* __restrict__ Whht,
    const float* __restrict__ b_ih, const float* __restrict__ b_hh,
    const float* __restrict__ Wp, const float* __restrict__ bp,
    const float* __restrict__ opb2, float* __restrict__ w, float* __restrict__ wb2) {
  int b = blockIdx.x, tid = threadIdx.x;
  __shared__ float hs[256];
  __shared__ float lg[8];
  __shared__ float wacc[8];
  float s = 0.f;
  for (int c = 0; c < 16; ++c) s += hpart[(b*16 + c)*256 + tid];
  hs[tid] = s * (1.0f/4096.0f);
  if (tid < 8) wacc[tid] = 0.f;
  __syncthreads();
  for (int l = 0; l < NL; ++l) {
    float g0 = 0.f, g1 = 0.f, g2 = 0.f;
    for (int d2 = 0; d2 < 256; ++d2) {
      float hv = hs[d2];
      g0 += Whht[d2*768 + tid]       * hv;
      g1 += Whht[d2*768 + 256 + tid] * hv;
      g2 += Whht[d2*768 + 512 + tid] * hv;
    }
    g0 += b_hh[tid]; g1 += b_hh[256 + tid]; g2 += b_hh[512 + tid];
    float r = 1.f / (1.f + expf(-(b_ih[tid] + g0)));
    float z = 1.f / (1.f + expf(-(b_ih[256 + tid] + g1)));
    float n = tanhf(b_ih[512 + tid] + r * g2);
    float hnew = (1.f - z) * n + z * hs[tid];
    __syncthreads();
    hs[tid] = hnew;
    __syncthreads();
    if (tid < 8) {
      float acc = bp[tid];
      for (int d2 = 0; d2 < 256; ++d2) acc += hs[d2] * Wp[d2*8 + tid];
      lg[tid] = acc;
    }
    __syncthreads();
    if (tid == 0) {
      float mx = lg[0];
      #pragma unroll
      for (int i = 1; i < 8; ++i) mx = fmaxf(mx, lg[i]);
      float sm = 0.f; float e[8];
      #pragma unroll
      for (int i = 0; i < 8; ++i) { e[i] = expf(lg[i] - mx); sm += e[i]; }
      #pragma unroll
      for (int i = 0; i < 8; ++i) wacc[i] += e[i] / sm;
    }
    __syncthreads();
  }
  if (tid < 8) w[b*8 + tid] = wacc[tid] * 0.25f;
  float acc = 0.f;
  #pragma unroll
  for (int v = 0; v < 8; ++v) acc += (wacc[v] * 0.25f) * opb2[v*256 + tid];
  wb2[b*256 + tid] = acc;
}

// ---------------- max-pool partials over t ----------------
__global__ void maxpool_kernel(const unsigned short* __restrict__ fusedB, float* __restrict__ mpart) {
  int c = blockIdx.x, b = blockIdx.y, d = threadIdx.x;
  const unsigned short* fp = &fusedB[((size_t)(b*TT + c*256))*256 + d];
  float m = -__builtin_inff();
  for (int i = 0; i < 256; ++i) m = fmaxf(m, b2f(fp[(size_t)i*256]));
  mpart[(b*16 + c)*256 + d] = m;
}

// ---------------- final: pooled @ Wo + bo ----------------
__global__ __launch_bounds__(256) void outproj_kernel(
    const float* __restrict__ mpart, const float* __restrict__ Wo,
    const float* __restrict__ bo, float* __restrict__ out) {
  int b = blockIdx.x, tid = threadIdx.x;
  __shared__ float pooled[256];
  float m = -__builtin_inff();
  for (int c = 0; c < 16; ++c) m = fmaxf(m, mpart[(b*16 + c)*256 + tid]);
  pooled[tid] = m;
  __syncthreads();
  float acc = bo[tid];
  for (int d = 0; d < 256; ++d) acc += pooled[d] * Wo[d*256 + tid];
  out[b*256 + tid] = acc;
}

// ---------------- host ----------------
extern "C" void kernel_launch(void* const* d_in, const int* in_sizes, int n_in,
                              void* d_out, int out_size, void* d_ws, size_t ws_size,
                              hipStream_t stream) {
  const float* x     = (const float*)d_in[0];
  const float* amask = (const float*)d_in[1];
  const float* Wq    = (const float*)d_in[2];
  const float* bq    = (const float*)d_in[3];
  const float* Wk    = (const float*)d_in[4];
  const float* bk    = (const float*)d_in[5];
  const float* W1f   = (const float*)d_in[8];
  const float* b1f   = (const float*)d_in[9];
  const float* W2f   = (const float*)d_in[10];
  const float* b2f   = (const float*)d_in[11];
  const float* ln_g  = (const float*)d_in[12];
  const float* ln_b  = (const float*)d_in[13];
  const float* Whh   = (const float*)d_in[14];
  const float* b_ih  = (const float*)d_in[15];
  const float* b_hh  = (const float*)d_in[16];
  const float* Wp    = (const float*)d_in[17];
  const float* bp    = (const float*)d_in[18];
  const float* opW1  = (const float*)d_in[19];
  const float* opb1  = (const float*)d_in[20];
  const float* opW2  = (const float*)d_in[21];
  const float* opb2  = (const float*)d_in[22];
  const float* Wo    = (const float*)d_in[23];
  const float* bo    = (const float*)d_in[24];
  (void)in_sizes; (void)n_in; (void)out_size; (void)ws_size;

  // workspace layout (liveness-overlapped; peak ~84 MB)
  char* ws = (char*)d_ws;
  float*          q      = (float*)(ws + 0);          // 2MB, dead after sim_topk
  float*          kk     = (float*)(ws + 2097152);    // 2MB, dead after sim_topk
  float*          candv  = (float*)(ws + 4194304);    // 8MB, dead after merge
  int*            candi  = (int*)  (ws + 12582912);   // 8MB, dead after merge
  unsigned short* rmb    = (unsigned short*)(ws + 20971520); // 8MB, dead after gemm<1>
  unsigned short* G1     = (unsigned short*)(ws + 29360128); // 16MB, dead after gemm<1>
  float*          preLN  = (float*)(ws + 46137344);   // 16MB, dead after ln
  unsigned short* G1all  = (unsigned short*)(ws + 0); // 64MB (0..64MB), written by gemm<2> when all above dead
  unsigned short* h      = (unsigned short*)(ws + 67108864); // 8MB, live through gemm<2>
  unsigned short* W1ft   = (unsigned short*)(ws + 75497472);
  unsigned short* W2ft   = (unsigned short*)(ws + 75759616);
  unsigned short* opW1t  = (unsigned short*)(ws + 76021760);
  unsigned short* opW2t  = (unsigned short*)(ws + 77070336);
  float*          Whht   = (float*)(ws + 78118912);
  float*          hpart  = (float*)(ws + 78905344);
  float*          wv     = (float*)(ws + 78970880);
  float*          wb2    = (float*)(ws + 78974976);
  float*          mpart  = (float*)(ws + 78979072);
  unsigned short* fusedB = (unsigned short*)(ws + 79044608); // 8MB

  prep_weights<<<5888, 256, 0, stream>>>(W1f, W2f, opW1, opW2, Whh, W1ft, W2ft, opW1t, opW2t, Whht);
  qk_proj<<<4096, 256, 0, stream>>>(x, Wq, bq, Wk, bk, q, kk);
  sim_topk<<<dim3(NCH, 8, BB), 256, 0, stream>>>(q, kk, amask, candv, candi);
  merge_gather<<<256, 256, 0, stream>>>(candv, candi, x, rmb);
  gemm_bf16<0><<<dim3(128, 4), 256, 0, stream>>>(rmb, W1ft, 512, 256, b1f, nullptr, nullptr, nullptr, G1);
  gemm_bf16<1><<<dim3(128, 2), 256, 0, stream>>>(G1, W2ft, 256, 512, b2f, rmb, nullptr, preLN, nullptr);
  ln_kernel<<<4096, 256, 0, stream>>>(preLN, ln_g, ln_b, h);
  hsum_kernel<<<dim3(16, 4), 256, 0, stream>>>(h, hpart);
  gru_kernel<<<4, 256, 0, stream>>>(hpart, Whht, b_ih, b_hh, Wp, bp, opb2, wv, wb2);
  gemm_bf16<2><<<dim3(128, 16), 256, 0, stream>>>(h, opW1t, 2048, 256, opb1, nullptr, wv, nullptr, G1all);
  gemm_bf16<3><<<dim3(128, 2), 256, 0, stream>>>(G1all, opW2t, 256, 2048, nullptr, nullptr, wb2, nullptr, fusedB);
  maxpool_kernel<<<dim3(16, 4), 256, 0, stream>>>(fusedB, mpart);
  outproj_kernel<<<4, 256, 0, stream>>>(mpart, Wo, bo, (float*)d_out);
}

// Round 4
// 407.629 us; speedup vs baseline: 1.4266x; 1.2442x over previous
//
#include <hip/hip_runtime.h>

// ---------------- constants ----------------
#define BB 4
#define TT 4096
#define DD 256
#define KQ 32
#define TOPK 4
#define NV 8
#define NL 4
#define MROWS (BB*TT)   // 16384
#define SCHUNK 512      // s-rows staged per LDS chunk in sim_scan

typedef __attribute__((ext_vector_type(8))) __bf16 bf16x8;
typedef __attribute__((ext_vector_type(4))) float  f32x4;

__device__ __forceinline__ unsigned short f2bf(float f) {
  union { float f; unsigned u; } un; un.f = f;
  unsigned r = un.u + 0x7fffu + ((un.u >> 16) & 1u);
  return (unsigned short)(r >> 16);
}
__device__ __forceinline__ float b2f(unsigned short s) {
  union { unsigned u; float f; } un; un.u = ((unsigned)s) << 16;
  return un.f;
}

// keep top-8 (desc) with first-seen-wins on ties
__device__ __forceinline__ void ins8(float val, int s, float v[8], int id[8]) {
  if (val <= v[7]) return;
  v[7] = val; id[7] = s;
  #pragma unroll
  for (int j = 7; j > 0; --j) {
    if (v[j] > v[j-1]) {
      float tv = v[j]; v[j] = v[j-1]; v[j-1] = tv;
      int   ti = id[j]; id[j] = id[j-1]; id[j-1] = ti;
    }
  }
}

// ---------------- weight prep: transpose + bf16 convert ----------------
__global__ __launch_bounds__(256) void prep_weights(
    const float* __restrict__ W1f, const float* __restrict__ W2f,
    const float* __restrict__ opW1, const float* __restrict__ opW2,
    const float* __restrict__ Whh,
    unsigned short* __restrict__ W1ft, unsigned short* __restrict__ W2ft,
    unsigned short* __restrict__ opW1t, unsigned short* __restrict__ opW2t,
    float* __restrict__ Whht) {
  int idx = blockIdx.x * 256 + threadIdx.x;
  if (idx < 131072) { int n = idx >> 8, d = idx & 255; W1ft[idx] = f2bf(W1f[d*512 + n]); return; }
  idx -= 131072;
  if (idx < 131072) { int n = idx >> 9, d = idx & 511; W2ft[idx] = f2bf(W2f[d*256 + n]); return; }
  idx -= 131072;
  if (idx < 524288) { int np = idx >> 8, d = idx & 255; int v = np >> 8, e = np & 255;
                      opW1t[idx] = f2bf(opW1[v*65536 + d*256 + e]); return; }
  idx -= 524288;
  if (idx < 524288) { int n = idx >> 11, kp = idx & 2047; int v = kp >> 8, k2 = kp & 255;
                      opW2t[idx] = f2bf(opW2[v*65536 + k2*256 + n]); return; }
  idx -= 524288;
  if (idx < 196608) { int d = idx / 768, j = idx - d*768; Whht[idx] = Whh[j*256 + d]; return; }
}

// ---------------- q/k projection (fp32 + bf16 copies) ----------------
__global__ __launch_bounds__(256) void qk_proj(
    const float* __restrict__ x, const float* __restrict__ Wq, const float* __restrict__ bq,
    const float* __restrict__ Wk, const float* __restrict__ bk,
    float* __restrict__ q, float* __restrict__ kk,
    unsigned short* __restrict__ qbf, unsigned short* __restrict__ kbf) {
  __shared__ float xs[1024];
  int tid = threadIdx.x;
  *(float4*)&xs[tid*4] = *(const float4*)&x[(size_t)blockIdx.x*1024 + tid*4];
  __syncthreads();
  int row = blockIdx.x*4 + (tid >> 6);
  int j = tid & 63;
  int jj = j & 31;
  const float* W = (j < 32) ? Wq : Wk;
  const float* xr = &xs[(tid >> 6) * 256];
  float acc = 0.f;
  #pragma unroll 8
  for (int d = 0; d < 256; ++d) acc += xr[d] * W[d*32 + jj];
  acc += (j < 32) ? bq[jj] : bk[jj];
  float* out = (j < 32) ? q : kk;
  unsigned short* outb = (j < 32) ? qbf : kbf;
  out[(size_t)row*32 + jj] = acc;
  outb[(size_t)row*32 + jj] = f2bf(acc);
}

// ---------------- sim scan via MFMA (approx top-8 per row) ----------------
// grid: (TT/64, BB), 256 threads (4 waves). Wave w owns q-rows q0+w*16..+15.
// C^T trick: mfma(A=k_frag, B=q_frag) -> C[s][q]: lane holds q-col (lane&15),
// s-rows (lane>>4)*4+r  => per-lane ins8, no cross-lane until final merge.
__global__ __launch_bounds__(256) void sim_scan(
    const unsigned short* __restrict__ qbf, const unsigned short* __restrict__ kbf,
    const float* __restrict__ mask, int* __restrict__ top8) {
  int b = blockIdx.y;
  int q0 = blockIdx.x * 64;
  int tid = threadIdx.x;
  int w = tid >> 6, lane = tid & 63;
  int l15 = lane & 15, lhi = lane >> 4;

  __shared__ unsigned short kfr[SCHUNK*32];  // 32KB, fragment-ordered
  __shared__ float ms[SCHUNK];
  __shared__ int mflag;

  int qrow = q0 + w*16 + l15;
  bf16x8 qf = *(const bf16x8*)&qbf[((size_t)b*TT + qrow)*32 + lhi*8];
  float mrow = mask[b*TT + qrow];

  float vtop[8]; int itop[8];
  #pragma unroll
  for (int r = 0; r < 8; ++r) { vtop[r] = -__builtin_inff(); itop[r] = 0; }

  for (int s0 = 0; s0 < TT; s0 += SCHUNK) {
    __syncthreads();
    if (tid == 0) mflag = 0;
    __syncthreads();
    int anyzero = 0;
    #pragma unroll
    for (int rr = 0; rr < 2; ++rr) {
      int s = rr*256 + tid;
      const unsigned short* src = &kbf[((size_t)b*TT + s0 + s)*32];
      uint4 d0 = *(const uint4*)(src);
      uint4 d1 = *(const uint4*)(src + 8);
      uint4 d2 = *(const uint4*)(src + 16);
      uint4 d3 = *(const uint4*)(src + 24);
      int fb = (s >> 4)*512 + (s & 15)*8;
      *(uint4*)&kfr[fb +   0] = d0;
      *(uint4*)&kfr[fb + 128] = d1;
      *(uint4*)&kfr[fb + 256] = d2;
      *(uint4*)&kfr[fb + 384] = d3;
      float mv = mask[b*TT + s0 + s];
      ms[s] = mv;
      if (mv == 0.f) anyzero = 1;
    }
    if (anyzero) mflag = 1;
    __syncthreads();
    bool useMask = (mflag != 0) || (mrow == 0.f);
    f32x4 z = {0.f, 0.f, 0.f, 0.f};
    for (int sf = 0; sf < 32; sf += 2) {
      bf16x8 a0 = *(const bf16x8*)&kfr[(sf+0)*512 + lane*8];
      bf16x8 a1 = *(const bf16x8*)&kfr[(sf+1)*512 + lane*8];
      f32x4 c0 = __builtin_amdgcn_mfma_f32_16x16x32_bf16(a0, qf, z, 0, 0, 0);
      f32x4 c1 = __builtin_amdgcn_mfma_f32_16x16x32_bf16(a1, qf, z, 0, 0, 0);
      int sb0 = s0 + (sf+0)*16 + lhi*4;
      int sb1 = s0 + (sf+1)*16 + lhi*4;
      #pragma unroll
      for (int r = 0; r < 4; ++r) {
        float v0 = c0[r], v1 = c1[r];
        if (useMask) {
          if (mrow * ms[(sf+0)*16 + lhi*4 + r] == 0.f) v0 = -1e9f;
          if (mrow * ms[(sf+1)*16 + lhi*4 + r] == 0.f) v1 = -1e9f;
        }
        ins8(v0, sb0 + r, vtop, itop);
        ins8(v1, sb1 + r, vtop, itop);
      }
    }
  }
  // final 4-lane merge per q-row (reuse kfr as scratch)
  __syncthreads();
  float* vsh = (float*)kfr;                 // 2048 floats (8KB)
  int*   ish = (int*)(kfr + 8192);          // next 8KB
  #pragma unroll
  for (int r = 0; r < 8; ++r) { vsh[tid*8 + r] = vtop[r]; ish[tid*8 + r] = itop[r]; }
  __syncthreads();
  if (lane < 16) {
    int qr = q0 + w*16 + lane;
    float v2[8]; int i2[8];
    #pragma unroll
    for (int r = 0; r < 8; ++r) { v2[r] = -__builtin_inff(); i2[r] = 0; }
    for (int h = 0; h < 4; ++h) {
      int src = w*64 + h*16 + lane;
      #pragma unroll
      for (int r = 0; r < 8; ++r) ins8(vsh[src*8 + r], ish[src*8 + r], v2, i2);
    }
    int* dst = &top8[((size_t)b*TT + qr)*8];
    #pragma unroll
    for (int r = 0; r < 8; ++r) dst[r] = i2[r];
  }
}

// ---------------- exact fp32 re-rank of 8 cands + gather + routed_mean ----------------
// 32 rows/block, 8 threads per row
__global__ __launch_bounds__(256) void refine_gather(
    const int* __restrict__ top8, const float* __restrict__ q, const float* __restrict__ kk,
    const float* __restrict__ mask, const float* __restrict__ x,
    unsigned short* __restrict__ rmb) {
  int row0 = blockIdx.x * 32;
  int tid = threadIdx.x;
  int rl = tid >> 3, cs = tid & 7;
  int row = row0 + rl;
  int b = row >> 12;
  int cand = top8[(size_t)row*8 + cs];
  const float* qp = &q[(size_t)row*32];
  const float* kp = &kk[((size_t)(b << 12) + cand)*32];
  float acc = 0.f;
  #pragma unroll
  for (int i = 0; i < 32; ++i) acc += qp[i]*kp[i];
  if (mask[row] * mask[(b << 12) + cand] == 0.f) acc = -1e9f;
  __shared__ float sv[256];
  __shared__ int   si[256];
  __shared__ int   sel[32][4];
  sv[tid] = acc; si[tid] = cand;
  __syncthreads();
  if (cs == 0) {
    int base = rl*8;
    int c0 = -1, c1 = -1, c2 = -1, c3 = -1;
    #pragma unroll
    for (int r = 0; r < 4; ++r) {
      float bv = -__builtin_inff(); int bi = 0x7fffffff;
      for (int j = 0; j < 8; ++j) {
        float v = sv[base + j]; int ii = si[base + j];
        if (ii == c0 || ii == c1 || ii == c2 || ii == c3) continue;
        if (v > bv || (v == bv && ii < bi)) { bv = v; bi = ii; }
      }
      if (r == 0) c0 = bi; else if (r == 1) c1 = bi; else if (r == 2) c2 = bi; else c3 = bi;
      sel[rl][r] = bi;
    }
  }
  __syncthreads();
  // gather + mean: thread covers 32 cols of its row
  int cb = cs * 32;
  int i0 = sel[rl][0], i1 = sel[rl][1], i2 = sel[rl][2], i3 = sel[rl][3];
  const float* xb = &x[(size_t)b*TT*DD];
  #pragma unroll
  for (int d = 0; d < 32; d += 4) {
    float4 a = *(const float4*)&xb[(size_t)i0*DD + cb + d];
    float4 bb = *(const float4*)&xb[(size_t)i1*DD + cb + d];
    float4 c = *(const float4*)&xb[(size_t)i2*DD + cb + d];
    float4 e = *(const float4*)&xb[(size_t)i3*DD + cb + d];
    ushort4 o;
    o.x = f2bf((a.x + bb.x + c.x + e.x)*0.25f);
    o.y = f2bf((a.y + bb.y + c.y + e.y)*0.25f);
    o.z = f2bf((a.z + bb.z + c.z + e.z)*0.25f);
    o.w = f2bf((a.w + bb.w + c.w + e.w)*0.25f);
    *(ushort4*)&rmb[(size_t)row*DD + cb + d] = o;
  }
}

// ---------------- bf16 MFMA GEMM (128x128 tile), epilogue variants ----------------
template<int EPI>
__global__ __launch_bounds__(256) void gemm_bf16(
    const unsigned short* __restrict__ A, const unsigned short* __restrict__ Bt,
    int Ndim, int Kdim,
    const float* __restrict__ bias,
    const unsigned short* __restrict__ resB,
    const float* __restrict__ auxf,
    float* __restrict__ outF, unsigned short* __restrict__ outB) {
  __shared__ unsigned short As[128*64];
  __shared__ unsigned short Bs[128*64];
  int tid = threadIdx.x;
  int lane = tid & 63, wid = tid >> 6;
  int wm = wid >> 1, wn = wid & 1;
  int l16 = lane & 15, lhi = lane >> 4;
  int m0 = blockIdx.x * 128, n0 = blockIdx.y * 128;
  f32x4 acc[4][4] = {};
  for (int kt = 0; kt < Kdim; kt += 64) {
    __syncthreads();
    #pragma unroll
    for (int i = 0; i < 4; ++i) {
      int L = i*256 + tid;
      int r = L >> 3, c = L & 7;
      int cs = c ^ (r & 7);
      uint4 va = *(const uint4*)(A  + (size_t)(m0 + r)*Kdim + kt + c*8);
      *(uint4*)&As[r*64 + cs*8] = va;
      uint4 vb = *(const uint4*)(Bt + (size_t)(n0 + r)*Kdim + kt + c*8);
      *(uint4*)&Bs[r*64 + cs*8] = vb;
    }
    __syncthreads();
    #pragma unroll
    for (int ks = 0; ks < 2; ++ks) {
      bf16x8 af[4], bfr[4];
      int kc = ks*4 + lhi;
      #pragma unroll
      for (int f = 0; f < 4; ++f) {
        int ra = wm*64 + f*16 + l16;
        af[f]  = *(const bf16x8*)&As[ra*64 + ((kc ^ (ra & 7)))*8];
        int rb = wn*64 + f*16 + l16;
        bfr[f] = *(const bf16x8*)&Bs[rb*64 + ((kc ^ (rb & 7)))*8];
      }
      #pragma unroll
      for (int mf = 0; mf < 4; ++mf)
        #pragma unroll
        for (int nf = 0; nf < 4; ++nf)
          acc[mf][nf] = __builtin_amdgcn_mfma_f32_16x16x32_bf16(af[mf], bfr[nf], acc[mf][nf], 0, 0, 0);
    }
  }
  #pragma unroll
  for (int mf = 0; mf < 4; ++mf) {
    #pragma unroll
    for (int nf = 0; nf < 4; ++nf) {
      #pragma unroll
      for (int r = 0; r < 4; ++r) {
        int row = m0 + wm*64 + mf*16 + lhi*4 + r;
        int col = n0 + wn*64 + nf*16 + l16;
        float v = acc[mf][nf][r];
        if constexpr (EPI == 0) {
          v += bias[col];
          v = 0.5f * v * (1.0f + erff(v * 0.70710678118654752f));
          outB[(size_t)row*Ndim + col] = f2bf(v);
        } else if constexpr (EPI == 1) {
          v += bias[col] + b2f(resB[(size_t)row*Ndim + col]);
          outF[(size_t)row*Ndim + col] = v;
        } else if constexpr (EPI == 2) {
          v += bias[col];
          v = fmaxf(v, 0.0f) * auxf[(row >> 12)*8 + (col >> 8)];
          outB[(size_t)row*Ndim + col] = f2bf(v);
        } else {
          v += auxf[(row >> 12)*256 + col];
          outB[(size_t)row*Ndim + col] = f2bf(v);
        }
      }
    }
  }
}

// ---------------- LayerNorm: one wave per row ----------------
__global__ __launch_bounds__(256) void ln_kernel(
    const float* __restrict__ preLN, const float* __restrict__ g,
    const float* __restrict__ bta, unsigned short* __restrict__ h) {
  int tid = threadIdx.x;
  int lane = tid & 63;
  int row = blockIdx.x*4 + (tid >> 6);
  float4 v = *(const float4*)&preLN[(size_t)row*256 + lane*4];
  float s = v.x + v.y + v.z + v.w;
  #pragma unroll
  for (int o = 32; o > 0; o >>= 1) s += __shfl_xor(s, o);
  float mu = s * (1.0f/256.0f);
  float4 d; d.x = v.x-mu; d.y = v.y-mu; d.z = v.z-mu; d.w = v.w-mu;
  float s2 = d.x*d.x + d.y*d.y + d.z*d.z + d.w*d.w;
  #pragma unroll
  for (int o = 32; o > 0; o >>= 1) s2 += __shfl_xor(s2, o);
  float rstd = rsqrtf(s2 * (1.0f/256.0f) + 1e-5f);
  float4 gv = *(const float4*)&g[lane*4];
  float4 bv = *(const float4*)&bta[lane*4];
  ushort4 o;
  o.x = f2bf(d.x*rstd*gv.x + bv.x);
  o.y = f2bf(d.y*rstd*gv.y + bv.y);
  o.z = f2bf(d.z*rstd*gv.z + bv.z);
  o.w = f2bf(d.w*rstd*gv.w + bv.w);
  *(ushort4*)&h[(size_t)row*256 + lane*4] = o;
}

// ---------------- partial column-sum of h (64-row chunks) ----------------
__global__ __launch_bounds__(256) void hsum_kernel(const unsigned short* __restrict__ h, float* __restrict__ hpart) {
  int c = blockIdx.x, b = blockIdx.y, d = threadIdx.x;
  const unsigned short* hp = &h[((size_t)(b*TT + c*64))*256 + d];
  float s = 0.f;
  #pragma unroll 8
  for (int i = 0; i < 64; ++i) s += b2f(hp[i*256]);
  hpart[(b*64 + c)*256 + d] = s;
}

// ---------------- GRU + program logits + softmax-mean w + wb2 ----------------
__global__ __launch_bounds__(256) void gru_kernel(
    const float* __restrict__ hpart, const float* __restrict__ Whht,
    const float* __restrict__ b_ih, const float* __restrict__ b_hh,
    const float* __restrict__ Wp, const float* __restrict__ bp,
    const float* __restrict__ opb2, float* __restrict__ w, float* __restrict__ wb2) {
  int b = blockIdx.x, tid = threadIdx.x;
  __shared__ float hs[256];
  __shared__ float lg[8];
  __shared__ float wacc[8];
  float s = 0.f;
  for (int c = 0; c < 64; ++c) s += hpart[(b*64 + c)*256 + tid];
  hs[tid] = s * (1.0f/4096.0f);
  if (tid < 8) wacc[tid] = 0.f;
  __syncthreads();
  for (int l = 0; l < NL; ++l) {
    float g0 = 0.f, g1 = 0.f, g2 = 0.f;
    for (int d2 = 0; d2 < 256; ++d2) {
      float hv = hs[d2];
      g0 += Whht[d2*768 + tid]       * hv;
      g1 += Whht[d2*768 + 256 + tid] * hv;
      g2 += Whht[d2*768 + 512 + tid] * hv;
    }
    g0 += b_hh[tid]; g1 += b_hh[256 + tid]; g2 += b_hh[512 + tid];
    float r = 1.f / (1.f + expf(-(b_ih[tid] + g0)));
    float z = 1.f / (1.f + expf(-(b_ih[256 + tid] + g1)));
    float n = tanhf(b_ih[512 + tid] + r * g2);
    float hnew = (1.f - z) * n + z * hs[tid];
    __syncthreads();
    hs[tid] = hnew;
    __syncthreads();
    if (tid < 8) {
      float acc = bp[tid];
      for (int d2 = 0; d2 < 256; ++d2) acc += hs[d2] * Wp[d2*8 + tid];
      lg[tid] = acc;
    }
    __syncthreads();
    if (tid == 0) {
      float mx = lg[0];
      #pragma unroll
      for (int i = 1; i < 8; ++i) mx = fmaxf(mx, lg[i]);
      float sm = 0.f; float e[8];
      #pragma unroll
      for (int i = 0; i < 8; ++i) { e[i] = expf(lg[i] - mx); sm += e[i]; }
      #pragma unroll
      for (int i = 0; i < 8; ++i) wacc[i] += e[i] / sm;
    }
    __syncthreads();
  }
  if (tid < 8) w[b*8 + tid] = wacc[tid] * 0.25f;
  float acc = 0.f;
  #pragma unroll
  for (int v = 0; v < 8; ++v) acc += (wacc[v] * 0.25f) * opb2[v*256 + tid];
  wb2[b*256 + tid] = acc;
}

// ---------------- max-pool partials (64-row chunks) ----------------
__global__ __launch_bounds__(256) void maxpool_kernel(const unsigned short* __restrict__ fusedB, float* __restrict__ mpart) {
  int c = blockIdx.x, b = blockIdx.y, d = threadIdx.x;
  const unsigned short* fp = &fusedB[((size_t)(b*TT + c*64))*256 + d];
  float m = -__builtin_inff();
  #pragma unroll 8
  for (int i = 0; i < 64; ++i) m = fmaxf(m, b2f(fp[i*256]));
  mpart[(b*64 + c)*256 + d] = m;
}

// ---------------- final: pooled @ Wo + bo ----------------
__global__ __launch_bounds__(256) void outproj_kernel(
    const float* __restrict__ mpart, const float* __restrict__ Wo,
    const float* __restrict__ bo, float* __restrict__ out) {
  int b = blockIdx.x, tid = threadIdx.x;
  __shared__ float pooled[256];
  float m = -__builtin_inff();
  for (int c = 0; c < 64; ++c) m = fmaxf(m, mpart[(b*64 + c)*256 + tid]);
  pooled[tid] = m;
  __syncthreads();
  float acc = bo[tid];
  for (int d = 0; d < 256; ++d) acc += pooled[d] * Wo[d*256 + tid];
  out[b*256 + tid] = acc;
}

// ---------------- host ----------------
extern "C" void kernel_launch(void* const* d_in, const int* in_sizes, int n_in,
                              void* d_out, int out_size, void* d_ws, size_t ws_size,
                              hipStream_t stream) {
  const float* x     = (const float*)d_in[0];
  const float* amask = (const float*)d_in[1];
  const float* Wq    = (const float*)d_in[2];
  const float* bq    = (const float*)d_in[3];
  const float* Wk    = (const float*)d_in[4];
  const float* bk    = (const float*)d_in[5];
  const float* W1f   = (const float*)d_in[8];
  const float* b1f   = (const float*)d_in[9];
  const float* W2f   = (const float*)d_in[10];
  const float* b2f   = (const float*)d_in[11];
  const float* ln_g  = (const float*)d_in[12];
  const float* ln_b  = (const float*)d_in[13];
  const float* Whh   = (const float*)d_in[14];
  const float* b_ih  = (const float*)d_in[15];
  const float* b_hh  = (const float*)d_in[16];
  const float* Wp    = (const float*)d_in[17];
  const float* bp    = (const float*)d_in[18];
  const float* opW1  = (const float*)d_in[19];
  const float* opb1  = (const float*)d_in[20];
  const float* opW2  = (const float*)d_in[21];
  const float* opb2  = (const float*)d_in[22];
  const float* Wo    = (const float*)d_in[23];
  const float* bo    = (const float*)d_in[24];
  (void)in_sizes; (void)n_in; (void)out_size; (void)ws_size;

  // workspace layout (liveness-overlapped; peak ~84 MB)
  char* ws = (char*)d_ws;
  float*          q      = (float*)(ws + 0);                  // 2MB   } dead
  float*          kk     = (float*)(ws + 2097152);            // 2MB   } before
  unsigned short* qbf    = (unsigned short*)(ws + 4194304);   // 1MB   } gemm<2>
  unsigned short* kbf    = (unsigned short*)(ws + 5242880);   // 1MB   }
  int*            top8   = (int*)(ws + 6291456);              // 512KB }
  unsigned short* rmb    = (unsigned short*)(ws + 8388608);   // 8MB   } (dead after gemm<1>)
  unsigned short* G1     = (unsigned short*)(ws + 16777216);  // 16MB  }
  float*          preLN  = (float*)(ws + 33554432);           // 16MB  }
  unsigned short* G1all  = (unsigned short*)(ws + 0);         // 64MB overlays [0,64M) at gemm<2>
  unsigned short* h      = (unsigned short*)(ws + 67108864);  // 8MB, live through gemm<2>
  unsigned short* W1ft   = (unsigned short*)(ws + 75497472);
  unsigned short* W2ft   = (unsigned short*)(ws + 75759616);
  unsigned short* opW1t  = (unsigned short*)(ws + 76021760);
  unsigned short* opW2t  = (unsigned short*)(ws + 77070336);
  float*          Whht   = (float*)(ws + 78118912);
  float*          hpart  = (float*)(ws + 78905344);           // 256KB (B*64*256 f32)
  float*          wv     = (float*)(ws + 79167488);
  float*          wb2    = (float*)(ws + 79171584);
  float*          mpart  = (float*)(ws + 79175680);           // 256KB
  unsigned short* fusedB = (unsigned short*)(ws + 79441920);  // 8MB

  prep_weights<<<5888, 256, 0, stream>>>(W1f, W2f, opW1, opW2, Whh, W1ft, W2ft, opW1t, opW2t, Whht);
  qk_proj<<<4096, 256, 0, stream>>>(x, Wq, bq, Wk, bk, q, kk, qbf, kbf);
  sim_scan<<<dim3(TT/64, BB), 256, 0, stream>>>(qbf, kbf, amask, top8);
  refine_gather<<<512, 256, 0, stream>>>(top8, q, kk, amask, x, rmb);
  gemm_bf16<0><<<dim3(128, 4), 256, 0, stream>>>(rmb, W1ft, 512, 256, b1f, nullptr, nullptr, nullptr, G1);
  gemm_bf16<1><<<dim3(128, 2), 256, 0, stream>>>(G1, W2ft, 256, 512, b2f, rmb, nullptr, preLN, nullptr);
  ln_kernel<<<4096, 256, 0, stream>>>(preLN, ln_g, ln_b, h);
  hsum_kernel<<<dim3(64, BB), 256, 0, stream>>>(h, hpart);
  gru_kernel<<<4, 256, 0, stream>>>(hpart, Whht, b_ih, b_hh, Wp, bp, opb2, wv, wb2);
  gemm_bf16<2><<<dim3(128, 16), 256, 0, stream>>>(h, opW1t, 2048, 256, opb1, nullptr, wv, nullptr, G1all);
  gemm_bf16<3><<<dim3(128, 2), 256, 0, stream>>>(G1all, opW2t, 256, 2048, nullptr, nullptr, wb2, nullptr, fusedB);
  maxpool_kernel<<<dim3(64, BB), 256, 0, stream>>>(fusedB, mpart);
  outproj_kernel<<<4, 256, 0, stream>>>(mpart, Wo, bo, (float*)d_out);
}

// Round 5
// 334.869 us; speedup vs baseline: 1.7366x; 1.2173x over previous
//
#include <hip/hip_runtime.h>

// ---------------- constants ----------------
#define BB 4
#define TT 4096
#define DD 256
#define KQ 32
#define TOPK 4
#define NV 8
#define NL 4
#define MROWS (BB*TT)   // 16384
#define NSC 4           // s-chunk blocks in sim_scan
#define SSPAN 1024      // s-rows per sim_scan block
#define SCHUNK 512      // s-rows staged per LDS pass

typedef __attribute__((ext_vector_type(8))) __bf16 bf16x8;
typedef __attribute__((ext_vector_type(4))) float  f32x4;

__device__ __forceinline__ unsigned short f2bf(float f) {
  union { float f; unsigned u; } un; un.f = f;
  unsigned r = un.u + 0x7fffu + ((un.u >> 16) & 1u);
  return (unsigned short)(r >> 16);
}
__device__ __forceinline__ float b2f(unsigned short s) {
  union { unsigned u; float f; } un; un.u = ((unsigned)s) << 16;
  return un.f;
}

// keep top-4 (desc) with first-seen-wins on ties
__device__ __forceinline__ void ins4(float val, int s, float v[4], int id[4]) {
  if (val <= v[3]) return;
  v[3] = val; id[3] = s;
  #pragma unroll
  for (int j = 3; j > 0; --j) {
    if (v[j] > v[j-1]) {
      float tv = v[j]; v[j] = v[j-1]; v[j-1] = tv;
      int   ti = id[j]; id[j] = id[j-1]; id[j-1] = ti;
    }
  }
}

// ---------------- weight prep: transpose + bf16 convert ----------------
__global__ __launch_bounds__(256) void prep_weights(
    const float* __restrict__ W1f, const float* __restrict__ W2f,
    const float* __restrict__ opW1, const float* __restrict__ opW2,
    const float* __restrict__ Whh,
    unsigned short* __restrict__ W1ft, unsigned short* __restrict__ W2ft,
    unsigned short* __restrict__ opW1t, unsigned short* __restrict__ opW2t,
    float* __restrict__ Whht) {
  int idx = blockIdx.x * 256 + threadIdx.x;
  if (idx < 131072) { int n = idx >> 8, d = idx & 255; W1ft[idx] = f2bf(W1f[d*512 + n]); return; }
  idx -= 131072;
  if (idx < 131072) { int n = idx >> 9, d = idx & 511; W2ft[idx] = f2bf(W2f[d*256 + n]); return; }
  idx -= 131072;
  if (idx < 524288) { int np = idx >> 8, d = idx & 255; int v = np >> 8, e = np & 255;
                      opW1t[idx] = f2bf(opW1[v*65536 + d*256 + e]); return; }
  idx -= 524288;
  if (idx < 524288) { int n = idx >> 11, kp = idx & 2047; int v = kp >> 8, k2 = kp & 255;
                      opW2t[idx] = f2bf(opW2[v*65536 + k2*256 + n]); return; }
  idx -= 524288;
  if (idx < 196608) { int d = idx / 768, j = idx - d*768; Whht[idx] = Whh[j*256 + d]; return; }
}

// ---------------- q/k projection (fp32 + bf16 copies) ----------------
__global__ __launch_bounds__(256) void qk_proj(
    const float* __restrict__ x, const float* __restrict__ Wq, const float* __restrict__ bq,
    const float* __restrict__ Wk, const float* __restrict__ bk,
    float* __restrict__ q, float* __restrict__ kk,
    unsigned short* __restrict__ qbf, unsigned short* __restrict__ kbf) {
  __shared__ float xs[1024];
  int tid = threadIdx.x;
  *(float4*)&xs[tid*4] = *(const float4*)&x[(size_t)blockIdx.x*1024 + tid*4];
  __syncthreads();
  int row = blockIdx.x*4 + (tid >> 6);
  int j = tid & 63;
  int jj = j & 31;
  const float* W = (j < 32) ? Wq : Wk;
  const float* xr = &xs[(tid >> 6) * 256];
  float acc = 0.f;
  #pragma unroll 8
  for (int d = 0; d < 256; ++d) acc += xr[d] * W[d*32 + jj];
  acc += (j < 32) ? bq[jj] : bk[jj];
  float* out = (j < 32) ? q : kk;
  unsigned short* outb = (j < 32) ? qbf : kbf;
  out[(size_t)row*32 + jj] = acc;
  outb[(size_t)row*32 + jj] = f2bf(acc);
}

// ---------------- sim scan via MFMA (per-lane top-4 over lane's s-subset) ----------------
// grid: (TT/64, NSC, BB), 256 threads (4 waves). Wave w owns q-rows q0+w*16..+15.
// mfma(A=k_frag, B=q_frag) -> C[s][q]: lane (l15,lhi) holds q-col l15,
// s-rows tile*16+lhi*4+r  => per-lane ins4 over disjoint s-subsets.
// Union of 4 lanes x NSC chunks x 4 = 64 distinct candidates/row covers top-4.
__global__ __launch_bounds__(256) void sim_scan(
    const unsigned short* __restrict__ qbf, const unsigned short* __restrict__ kbf,
    const float* __restrict__ mask, int* __restrict__ candi) {
  int b = blockIdx.z, sc = blockIdx.y;
  int q0 = blockIdx.x * 64;
  int tid = threadIdx.x;
  int w = tid >> 6, lane = tid & 63;
  int l15 = lane & 15, lhi = lane >> 4;

  __shared__ unsigned short kfr[SCHUNK*32];  // 32KB, fragment-ordered
  __shared__ float ms[SCHUNK];
  __shared__ int mflag;

  int qrow = q0 + w*16 + l15;
  bf16x8 qf = *(const bf16x8*)&qbf[((size_t)b*TT + qrow)*32 + lhi*8];
  float mrow = mask[b*TT + qrow];

  float vtop[4]; int itop[4];
  #pragma unroll
  for (int r = 0; r < 4; ++r) { vtop[r] = -__builtin_inff(); itop[r] = 0; }

  for (int pass = 0; pass < SSPAN/SCHUNK; ++pass) {
    int s0 = sc*SSPAN + pass*SCHUNK;
    __syncthreads();
    if (tid == 0) mflag = 0;
    __syncthreads();
    int anyzero = 0;
    #pragma unroll
    for (int rr = 0; rr < 2; ++rr) {
      int s = rr*256 + tid;
      const unsigned short* src = &kbf[((size_t)b*TT + s0 + s)*32];
      uint4 d0 = *(const uint4*)(src);
      uint4 d1 = *(const uint4*)(src + 8);
      uint4 d2 = *(const uint4*)(src + 16);
      uint4 d3 = *(const uint4*)(src + 24);
      int fb = (s >> 4)*512 + (s & 15)*8;
      *(uint4*)&kfr[fb +   0] = d0;
      *(uint4*)&kfr[fb + 128] = d1;
      *(uint4*)&kfr[fb + 256] = d2;
      *(uint4*)&kfr[fb + 384] = d3;
      float mv = mask[b*TT + s0 + s];
      ms[s] = mv;
      if (mv == 0.f) anyzero = 1;
    }
    if (anyzero) mflag = 1;
    __syncthreads();
    bool useMask = (mflag != 0) || (mrow == 0.f);
    f32x4 z = {0.f, 0.f, 0.f, 0.f};
    for (int sf = 0; sf < SCHUNK/16; sf += 2) {
      bf16x8 a0 = *(const bf16x8*)&kfr[(sf+0)*512 + lane*8];
      bf16x8 a1 = *(const bf16x8*)&kfr[(sf+1)*512 + lane*8];
      f32x4 c0 = __builtin_amdgcn_mfma_f32_16x16x32_bf16(a0, qf, z, 0, 0, 0);
      f32x4 c1 = __builtin_amdgcn_mfma_f32_16x16x32_bf16(a1, qf, z, 0, 0, 0);
      int sb0 = s0 + (sf+0)*16 + lhi*4;
      int sb1 = s0 + (sf+1)*16 + lhi*4;
      #pragma unroll
      for (int r = 0; r < 4; ++r) {
        float v0 = c0[r], v1 = c1[r];
        if (useMask) {
          if (mrow * ms[(sf+0)*16 + lhi*4 + r] == 0.f) v0 = -1e9f;
          if (mrow * ms[(sf+1)*16 + lhi*4 + r] == 0.f) v1 = -1e9f;
        }
        ins4(v0, sb0 + r, vtop, itop);
        ins4(v1, sb1 + r, vtop, itop);
      }
    }
  }
  int* dst = &candi[((size_t)(b*TT + qrow))*64 + sc*16 + lhi*4];
  #pragma unroll
  for (int r = 0; r < 4; ++r) dst[r] = itop[r];
}

// ---------------- exact fp32 re-rank of 64 cands + gather + routed_mean ----------------
// 4 rows/block, 64 lanes per row (one wave each)
__global__ __launch_bounds__(256) void refine_gather(
    const int* __restrict__ candi, const float* __restrict__ q, const float* __restrict__ kk,
    const float* __restrict__ mask, const float* __restrict__ x,
    unsigned short* __restrict__ rmb) {
  int row0 = blockIdx.x * 4;
  int tid = threadIdx.x;
  int rl = tid >> 6, c = tid & 63;
  int row = row0 + rl;
  int b = row >> 12;
  int cand = candi[(size_t)row*64 + c];
  const float* qp = &q[(size_t)row*32];
  const float* kp = &kk[((size_t)(b << 12) + cand)*32];
  float v = 0.f;
  #pragma unroll
  for (int i = 0; i < 32; i += 4) {
    float4 qv = *(const float4*)&qp[i];
    float4 kv = *(const float4*)&kp[i];
    v += qv.x*kv.x + qv.y*kv.y + qv.z*kv.z + qv.w*kv.w;
  }
  if (mask[row] * mask[(b << 12) + cand] == 0.f) v = -1e9f;
  // 4 rounds of wave argmax (value desc, index asc)
  __shared__ int sel[4][4];
  int myc = cand;
  #pragma unroll
  for (int r = 0; r < 4; ++r) {
    float bv = v; int bi = myc;
    #pragma unroll
    for (int o = 32; o > 0; o >>= 1) {
      float ov = __shfl_xor(bv, o);
      int   oi = __shfl_xor(bi, o);
      if (ov > bv || (ov == bv && oi < bi)) { bv = ov; bi = oi; }
    }
    if (c == 0) sel[rl][r] = bi;
    if (myc == bi) v = -__builtin_inff();
  }
  __syncthreads();
  // gather + mean: thread covers 4 cols of its row
  int i0 = sel[rl][0], i1 = sel[rl][1], i2 = sel[rl][2], i3 = sel[rl][3];
  const float* xb = &x[(size_t)b*TT*DD];
  float4 a = *(const float4*)&xb[(size_t)i0*DD + c*4];
  float4 bb = *(const float4*)&xb[(size_t)i1*DD + c*4];
  float4 cc = *(const float4*)&xb[(size_t)i2*DD + c*4];
  float4 e = *(const float4*)&xb[(size_t)i3*DD + c*4];
  ushort4 o;
  o.x = f2bf((a.x + bb.x + cc.x + e.x)*0.25f);
  o.y = f2bf((a.y + bb.y + cc.y + e.y)*0.25f);
  o.z = f2bf((a.z + bb.z + cc.z + e.z)*0.25f);
  o.w = f2bf((a.w + bb.w + cc.w + e.w)*0.25f);
  *(ushort4*)&rmb[(size_t)row*DD + c*4] = o;
}

// ---------------- bf16 MFMA GEMM (128x128 tile), epilogue variants ----------------
template<int EPI>
__global__ __launch_bounds__(256) void gemm_bf16(
    const unsigned short* __restrict__ A, const unsigned short* __restrict__ Bt,
    int Ndim, int Kdim,
    const float* __restrict__ bias,
    const unsigned short* __restrict__ resB,
    const float* __restrict__ auxf,
    float* __restrict__ outF, unsigned short* __restrict__ outB) {
  __shared__ unsigned short As[128*64];
  __shared__ unsigned short Bs[128*64];
  int tid = threadIdx.x;
  int lane = tid & 63, wid = tid >> 6;
  int wm = wid >> 1, wn = wid & 1;
  int l16 = lane & 15, lhi = lane >> 4;
  int m0 = blockIdx.x * 128, n0 = blockIdx.y * 128;
  f32x4 acc[4][4] = {};
  for (int kt = 0; kt < Kdim; kt += 64) {
    __syncthreads();
    #pragma unroll
    for (int i = 0; i < 4; ++i) {
      int L = i*256 + tid;
      int r = L >> 3, c = L & 7;
      int cs = c ^ (r & 7);
      uint4 va = *(const uint4*)(A  + (size_t)(m0 + r)*Kdim + kt + c*8);
      *(uint4*)&As[r*64 + cs*8] = va;
      uint4 vb = *(const uint4*)(Bt + (size_t)(n0 + r)*Kdim + kt + c*8);
      *(uint4*)&Bs[r*64 + cs*8] = vb;
    }
    __syncthreads();
    #pragma unroll
    for (int ks = 0; ks < 2; ++ks) {
      bf16x8 af[4], bfr[4];
      int kc = ks*4 + lhi;
      #pragma unroll
      for (int f = 0; f < 4; ++f) {
        int ra = wm*64 + f*16 + l16;
        af[f]  = *(const bf16x8*)&As[ra*64 + ((kc ^ (ra & 7)))*8];
        int rb = wn*64 + f*16 + l16;
        bfr[f] = *(const bf16x8*)&Bs[rb*64 + ((kc ^ (rb & 7)))*8];
      }
      #pragma unroll
      for (int mf = 0; mf < 4; ++mf)
        #pragma unroll
        for (int nf = 0; nf < 4; ++nf)
          acc[mf][nf] = __builtin_amdgcn_mfma_f32_16x16x32_bf16(af[mf], bfr[nf], acc[mf][nf], 0, 0, 0);
    }
  }
  #pragma unroll
  for (int mf = 0; mf < 4; ++mf) {
    #pragma unroll
    for (int nf = 0; nf < 4; ++nf) {
      #pragma unroll
      for (int r = 0; r < 4; ++r) {
        int row = m0 + wm*64 + mf*16 + lhi*4 + r;
        int col = n0 + wn*64 + nf*16 + l16;
        float v = acc[mf][nf][r];
        if constexpr (EPI == 0) {
          v += bias[col];
          v = 0.5f * v * (1.0f + erff(v * 0.70710678118654752f));
          outB[(size_t)row*Ndim + col] = f2bf(v);
        } else if constexpr (EPI == 1) {
          v += bias[col] + b2f(resB[(size_t)row*Ndim + col]);
          outF[(size_t)row*Ndim + col] = v;
        } else if constexpr (EPI == 2) {
          v += bias[col];
          v = fmaxf(v, 0.0f) * auxf[(row >> 12)*8 + (col >> 8)];
          outB[(size_t)row*Ndim + col] = f2bf(v);
        } else {
          v += auxf[(row >> 12)*256 + col];
          outB[(size_t)row*Ndim + col] = f2bf(v);
        }
      }
    }
  }
}

// ---------------- LayerNorm: one wave per row ----------------
__global__ __launch_bounds__(256) void ln_kernel(
    const float* __restrict__ preLN, const float* __restrict__ g,
    const float* __restrict__ bta, unsigned short* __restrict__ h) {
  int tid = threadIdx.x;
  int lane = tid & 63;
  int row = blockIdx.x*4 + (tid >> 6);
  float4 v = *(const float4*)&preLN[(size_t)row*256 + lane*4];
  float s = v.x + v.y + v.z + v.w;
  #pragma unroll
  for (int o = 32; o > 0; o >>= 1) s += __shfl_xor(s, o);
  float mu = s * (1.0f/256.0f);
  float4 d; d.x = v.x-mu; d.y = v.y-mu; d.z = v.z-mu; d.w = v.w-mu;
  float s2 = d.x*d.x + d.y*d.y + d.z*d.z + d.w*d.w;
  #pragma unroll
  for (int o = 32; o > 0; o >>= 1) s2 += __shfl_xor(s2, o);
  float rstd = rsqrtf(s2 * (1.0f/256.0f) + 1e-5f);
  float4 gv = *(const float4*)&g[lane*4];
  float4 bv = *(const float4*)&bta[lane*4];
  ushort4 o;
  o.x = f2bf(d.x*rstd*gv.x + bv.x);
  o.y = f2bf(d.y*rstd*gv.y + bv.y);
  o.z = f2bf(d.z*rstd*gv.z + bv.z);
  o.w = f2bf(d.w*rstd*gv.w + bv.w);
  *(ushort4*)&h[(size_t)row*256 + lane*4] = o;
}

// ---------------- partial column-sum of h (64-row chunks) ----------------
__global__ __launch_bounds__(256) void hsum_kernel(const unsigned short* __restrict__ h, float* __restrict__ hpart) {
  int c = blockIdx.x, b = blockIdx.y, d = threadIdx.x;
  const unsigned short* hp = &h[((size_t)(b*TT + c*64))*256 + d];
  float s = 0.f;
  #pragma unroll 8
  for (int i = 0; i < 64; ++i) s += b2f(hp[i*256]);
  hpart[(b*64 + c)*256 + d] = s;
}

// ---------------- GRU + program logits + softmax-mean w + wb2 ----------------
__global__ __launch_bounds__(256) void gru_kernel(
    const float* __restrict__ hpart, const float* __restrict__ Whht,
    const float* __restrict__ b_ih, const float* __restrict__ b_hh,
    const float* __restrict__ Wp, const float* __restrict__ bp,
    const float* __restrict__ opb2, float* __restrict__ w, float* __restrict__ wb2) {
  int b = blockIdx.x, tid = threadIdx.x;
  __shared__ float hs[256];
  __shared__ float lg[8];
  __shared__ float wacc[8];
  float s = 0.f;
  for (int c = 0; c < 64; ++c) s += hpart[(b*64 + c)*256 + tid];
  hs[tid] = s * (1.0f/4096.0f);
  if (tid < 8) wacc[tid] = 0.f;
  __syncthreads();
  for (int l = 0; l < NL; ++l) {
    float g0 = 0.f, g1 = 0.f, g2 = 0.f;
    for (int d2 = 0; d2 < 256; ++d2) {
      float hv = hs[d2];
      g0 += Whht[d2*768 + tid]       * hv;
      g1 += Whht[d2*768 + 256 + tid] * hv;
      g2 += Whht[d2*768 + 512 + tid] * hv;
    }
    g0 += b_hh[tid]; g1 += b_hh[256 + tid]; g2 += b_hh[512 + tid];
    float r = 1.f / (1.f + expf(-(b_ih[tid] + g0)));
    float z = 1.f / (1.f + expf(-(b_ih[256 + tid] + g1)));
    float n = tanhf(b_ih[512 + tid] + r * g2);
    float hnew = (1.f - z) * n + z * hs[tid];
    __syncthreads();
    hs[tid] = hnew;
    __syncthreads();
    if (tid < 8) {
      float acc = bp[tid];
      for (int d2 = 0; d2 < 256; ++d2) acc += hs[d2] * Wp[d2*8 + tid];
      lg[tid] = acc;
    }
    __syncthreads();
    if (tid == 0) {
      float mx = lg[0];
      #pragma unroll
      for (int i = 1; i < 8; ++i) mx = fmaxf(mx, lg[i]);
      float sm = 0.f; float e[8];
      #pragma unroll
      for (int i = 0; i < 8; ++i) { e[i] = expf(lg[i] - mx); sm += e[i]; }
      #pragma unroll
      for (int i = 0; i < 8; ++i) wacc[i] += e[i] / sm;
    }
    __syncthreads();
  }
  if (tid < 8) w[b*8 + tid] = wacc[tid] * 0.25f;
  float acc = 0.f;
  #pragma unroll
  for (int v = 0; v < 8; ++v) acc += (wacc[v] * 0.25f) * opb2[v*256 + tid];
  wb2[b*256 + tid] = acc;
}

// ---------------- max-pool partials (64-row chunks) ----------------
__global__ __launch_bounds__(256) void maxpool_kernel(const unsigned short* __restrict__ fusedB, float* __restrict__ mpart) {
  int c = blockIdx.x, b = blockIdx.y, d = threadIdx.x;
  const unsigned short* fp = &fusedB[((size_t)(b*TT + c*64))*256 + d];
  float m = -__builtin_inff();
  #pragma unroll 8
  for (int i = 0; i < 64; ++i) m = fmaxf(m, b2f(fp[i*256]));
  mpart[(b*64 + c)*256 + d] = m;
}

// ---------------- final: pooled @ Wo + bo ----------------
__global__ __launch_bounds__(256) void outproj_kernel(
    const float* __restrict__ mpart, const float* __restrict__ Wo,
    const float* __restrict__ bo, float* __restrict__ out) {
  int b = blockIdx.x, tid = threadIdx.x;
  __shared__ float pooled[256];
  float m = -__builtin_inff();
  for (int c = 0; c < 64; ++c) m = fmaxf(m, mpart[(b*64 + c)*256 + tid]);
  pooled[tid] = m;
  __syncthreads();
  float acc = bo[tid];
  for (int d = 0; d < 256; ++d) acc += pooled[d] * Wo[d*256 + tid];
  out[b*256 + tid] = acc;
}

// ---------------- host ----------------
extern "C" void kernel_launch(void* const* d_in, const int* in_sizes, int n_in,
                              void* d_out, int out_size, void* d_ws, size_t ws_size,
                              hipStream_t stream) {
  const float* x     = (const float*)d_in[0];
  const float* amask = (const float*)d_in[1];
  const float* Wq    = (const float*)d_in[2];
  const float* bq    = (const float*)d_in[3];
  const float* Wk    = (const float*)d_in[4];
  const float* bk    = (const float*)d_in[5];
  const float* W1f   = (const float*)d_in[8];
  const float* b1f   = (const float*)d_in[9];
  const float* W2f   = (const float*)d_in[10];
  const float* b2f   = (const float*)d_in[11];
  const float* ln_g  = (const float*)d_in[12];
  const float* ln_b  = (const float*)d_in[13];
  const float* Whh   = (const float*)d_in[14];
  const float* b_ih  = (const float*)d_in[15];
  const float* b_hh  = (const float*)d_in[16];
  const float* Wp    = (const float*)d_in[17];
  const float* bp    = (const float*)d_in[18];
  const float* opW1  = (const float*)d_in[19];
  const float* opb1  = (const float*)d_in[20];
  const float* opW2  = (const float*)d_in[21];
  const float* opb2  = (const float*)d_in[22];
  const float* Wo    = (const float*)d_in[23];
  const float* bo    = (const float*)d_in[24];
  (void)in_sizes; (void)n_in; (void)out_size; (void)ws_size;

  // workspace layout (liveness-overlapped; peak ~88 MB)
  char* ws = (char*)d_ws;
  float*          q      = (float*)(ws + 0);                  // 2MB   } dead
  float*          kk     = (float*)(ws + 2097152);            // 2MB   } before
  unsigned short* qbf    = (unsigned short*)(ws + 4194304);   // 1MB   } gemm<2>
  unsigned short* kbf    = (unsigned short*)(ws + 5242880);   // 1MB   }
  int*            candi  = (int*)(ws + 6291456);              // 4MB   }
  unsigned short* rmb    = (unsigned short*)(ws + 10485760);  // 8MB   } (dead after gemm<1>)
  unsigned short* G1     = (unsigned short*)(ws + 18874368);  // 16MB  }
  float*          preLN  = (float*)(ws + 35651584);           // 16MB  }
  unsigned short* G1all  = (unsigned short*)(ws + 0);         // 64MB overlays [0,64M) at gemm<2>
  unsigned short* h      = (unsigned short*)(ws + 67108864);  // 8MB, live through gemm<2>
  unsigned short* W1ft   = (unsigned short*)(ws + 75497472);
  unsigned short* W2ft   = (unsigned short*)(ws + 75759616);
  unsigned short* opW1t  = (unsigned short*)(ws + 76021760);
  unsigned short* opW2t  = (unsigned short*)(ws + 77070336);
  float*          Whht   = (float*)(ws + 78118912);
  float*          hpart  = (float*)(ws + 78905344);           // 256KB (B*64*256 f32)
  float*          wv     = (float*)(ws + 79167488);
  float*          wb2    = (float*)(ws + 79171584);
  float*          mpart  = (float*)(ws + 79175680);           // 256KB
  unsigned short* fusedB = (unsigned short*)(ws + 79441920);  // 8MB

  prep_weights<<<5888, 256, 0, stream>>>(W1f, W2f, opW1, opW2, Whh, W1ft, W2ft, opW1t, opW2t, Whht);
  qk_proj<<<4096, 256, 0, stream>>>(x, Wq, bq, Wk, bk, q, kk, qbf, kbf);
  sim_scan<<<dim3(TT/64, NSC, BB), 256, 0, stream>>>(qbf, kbf, amask, candi);
  refine_gather<<<4096, 256, 0, stream>>>(candi, q, kk, amask, x, rmb);
  gemm_bf16<0><<<dim3(128, 4), 256, 0, stream>>>(rmb, W1ft, 512, 256, b1f, nullptr, nullptr, nullptr, G1);
  gemm_bf16<1><<<dim3(128, 2), 256, 0, stream>>>(G1, W2ft, 256, 512, b2f, rmb, nullptr, preLN, nullptr);
  ln_kernel<<<4096, 256, 0, stream>>>(preLN, ln_g, ln_b, h);
  hsum_kernel<<<dim3(64, BB), 256, 0, stream>>>(h, hpart);
  gru_kernel<<<4, 256, 0, stream>>>(hpart, Whht, b_ih, b_hh, Wp, bp, opb2, wv, wb2);
  gemm_bf16<2><<<dim3(128, 16), 256, 0, stream>>>(h, opW1t, 2048, 256, opb1, nullptr, wv, nullptr, G1all);
  gemm_bf16<3><<<dim3(128, 2), 256, 0, stream>>>(G1all, opW2t, 256, 2048, nullptr, nullptr, wb2, nullptr, fusedB);
  maxpool_kernel<<<dim3(64, BB), 256, 0, stream>>>(fusedB, mpart);
  outproj_kernel<<<4, 256, 0, stream>>>(mpart, Wo, bo, (float*)d_out);
}